// Round 6
// baseline (661.971 us; speedup 1.0000x reference)
//
#include <hip/hip_runtime.h>
#include <hip/hip_cooperative_groups.h>
#include <math.h>

namespace cg = cooperative_groups;

#define N_NODES 50000
#define N_EDGES 800000
#define IN_DIM 32
#define HIDDEN 64
#define Z_DIM 32
#define SCAN_B 256
#define NB_SCAN ((N_NODES + SCAN_B - 1) / SCAN_B)   // 196
#define N_XCD 8
#define NPX ((N_NODES + N_XCD - 1) / N_XCD)         // 6250 nodes per XCD range
#define SLICE 2048
#define N_SLICE ((N_EDGES + SLICE - 1) / SLICE)     // 391
#define CPAD 16                                     // cnt stride: 1 line/node
#define GRID 512                                    // co-resident: 2 blocks/CU worst-case

// bf16 (stored as ushort) <-> f32 helpers, RNE
__device__ __forceinline__ unsigned short f2bf(float f) {
    unsigned int u = __float_as_uint(f);
    u += 0x7fffu + ((u >> 16) & 1u);
    return (unsigned short)(u >> 16);
}

// wave-local edge dtype detect: int64 LE values < 2^31 have all-zero odd words.
__device__ __forceinline__ int detect64(const int* raw) {
    int lane = threadIdx.x & 63;
    int odd = raw[2 * lane + 1];
    unsigned long long b = __ballot(odd != 0);
    return (b == 0ULL) ? 1 : 0;
}

// 8 bf16 (packed in uint4) FMA into acc[8]
__device__ __forceinline__ void fma8(float w, uint4 f, float acc[8]) {
    acc[0] = fmaf(w, __uint_as_float(f.x << 16),         acc[0]);
    acc[1] = fmaf(w, __uint_as_float(f.x & 0xffff0000u), acc[1]);
    acc[2] = fmaf(w, __uint_as_float(f.y << 16),         acc[2]);
    acc[3] = fmaf(w, __uint_as_float(f.y & 0xffff0000u), acc[3]);
    acc[4] = fmaf(w, __uint_as_float(f.z << 16),         acc[4]);
    acc[5] = fmaf(w, __uint_as_float(f.z & 0xffff0000u), acc[5]);
    acc[6] = fmaf(w, __uint_as_float(f.w << 16),         acc[6]);
    acc[7] = fmaf(w, __uint_as_float(f.w & 0xffff0000u), acc[7]);
}
__device__ __forceinline__ void mul8(float w, uint4 f, float acc[8]) {
    acc[0] = w * __uint_as_float(f.x << 16);
    acc[1] = w * __uint_as_float(f.x & 0xffff0000u);
    acc[2] = w * __uint_as_float(f.y << 16);
    acc[3] = w * __uint_as_float(f.y & 0xffff0000u);
    acc[4] = w * __uint_as_float(f.z << 16);
    acc[5] = w * __uint_as_float(f.z & 0xffff0000u);
    acc[6] = w * __uint_as_float(f.w << 16);
    acc[7] = w * __uint_as_float(f.w & 0xffff0000u);
}

// 64-wide aggregation. Edge batch staged into the wave's LDS slot, then
// ds_read per 8-edge group; uint4 feature gathers (8 lanes x 16B = 128B row,
// 8 edges per load instruction). Masked slots hold (s=0,w=0).
__device__ __forceinline__ void agg64(int e0, int e1, int2 pr,
                                      const int2* __restrict__ ep,
                                      const uint4* __restrict__ g4,
                                      int2* eb, int lane, int gsel, int c,
                                      float acc[8]) {
    for (int b0 = e0; b0 < e1; b0 += 64) {
        int cnt = e1 - b0; cnt = cnt > 64 ? 64 : cnt;        // uniform
        eb[lane] = pr;                                       // stage batch
        for (int j = 0; j < cnt; j += 16) {
            int2 ew0 = eb[j + gsel];                         // gsel in 0..7
            int2 ew1 = eb[j + 8 + gsel];
            uint4 f0 = g4[(size_t)ew0.x * 8 + c];
            uint4 f1 = g4[(size_t)ew1.x * 8 + c];
            fma8(__int_as_float(ew0.y), f0, acc);
            fma8(__int_as_float(ew1.y), f1, acc);
        }
        if (b0 + 64 < e1) {                                  // rare extra batch
            pr = make_int2(0, 0);
            int idx = b0 + 64 + lane;
            if (idx < e1) pr = ep[idx];
        }
    }
}

// 32-wide aggregation: 4 lanes x 16B cover one 64B row -> 16 edges per load.
__device__ __forceinline__ void agg32(int e0, int e1, int2 pr,
                                      const int2* __restrict__ ep,
                                      const uint4* __restrict__ x4,
                                      int2* eb, int lane, int gsel, int c,
                                      float acc[8]) {
    for (int b0 = e0; b0 < e1; b0 += 64) {
        int cnt = e1 - b0; cnt = cnt > 64 ? 64 : cnt;
        eb[lane] = pr;
        for (int j = 0; j < cnt; j += 32) {
            int2 ew0 = eb[j + gsel];                         // gsel in 0..15
            int2 ew1 = eb[j + 16 + gsel];
            uint4 f0 = x4[(size_t)ew0.x * 4 + c];
            uint4 f1 = x4[(size_t)ew1.x * 4 + c];
            fma8(__int_as_float(ew0.y), f0, acc);
            fma8(__int_as_float(ew1.y), f1, acc);
        }
        if (b0 + 64 < e1) {
            pr = make_int2(0, 0);
            int idx = b0 + 64 + lane;
            if (idx < e1) pr = ep[idx];
        }
    }
}

// ---------------------------------------------------------------------------
// One cooperative kernel; phases separated by grid.sync(). Rationale: the
// 7-dispatch pipeline plateaued at ~250us while the summed intrinsic work is
// ~100us -- dispatch boundaries (launch + ramp + drain) dominated. A grid
// sync costs ~2-5us vs ~15-25us per dispatch boundary, and LDS (sx) persists.
__global__ __launch_bounds__(256, 2) void mega_kernel(
        const float* __restrict__ x, const void* __restrict__ raw,
        const float* __restrict__ W1, const float* __restrict__ b1,
        const float* __restrict__ W2, const float* __restrict__ b2,
        const float* __restrict__ Wmu, const float* __restrict__ bmu,
        const float* __restrict__ Wlv, const float* __restrict__ blv,
        const float* __restrict__ eps, float* __restrict__ outz,
        int2* __restrict__ ep, ushort2* __restrict__ ep0,
        unsigned short* __restrict__ rank, int* __restrict__ pre,
        int* __restrict__ cnt, float* __restrict__ dinv,
        int* __restrict__ bsum, unsigned short* __restrict__ xb,
        unsigned short* __restrict__ G, unsigned short* __restrict__ H) {
    cg::grid_group gg = cg::this_grid();
    __shared__ int   sb[256];
    __shared__ int   sx[256];          // persistent bsum exclusive prefix
    __shared__ int2  ebuf[4][64];
    __shared__ float sq[4][64];

    const int tid  = threadIdx.x;
    const int nthr = GRID * 256;
    const int gi0  = (int)blockIdx.x * 256 + tid;
    const int lane = tid & 63;
    const int wav  = tid >> 6;
    int2* eb = &ebuf[wav][0];

    // ---- Phase A: prep (x->bf16, cnt zero, edge compaction to ushort2)
    int is64 = detect64((const int*)raw);
    for (int i = gi0; i < N_NODES * IN_DIM; i += nthr) xb[i] = f2bf(x[i]);
    for (int i = gi0; i < N_NODES * CPAD; i += nthr) cnt[i] = 0;
    if (is64) {
        const long long* r = (const long long*)raw;
        for (int e = gi0; e < N_EDGES; e += nthr)
            ep0[e] = make_ushort2((unsigned short)(int)r[e],
                                  (unsigned short)(int)r[N_EDGES + e]);
    } else {
        const int* r = (const int*)raw;
        for (int e = gi0; e < N_EDGES; e += nthr)
            ep0[e] = make_ushort2((unsigned short)r[e],
                                  (unsigned short)r[N_EDGES + e]);
    }
    gg.sync();

    // ---- Phase B: XCD-partitioned degree hist + rank capture
    {
        int xcd = (int)blockIdx.x & (N_XCD - 1);
        int lo = xcd * NPX, hi2 = lo + NPX;
        int nslb = GRID / N_XCD;                      // 64 blocks per xcd
        for (int sl = (int)blockIdx.x >> 3; sl < N_SLICE; sl += nslb) {
            int base = sl * SLICE;
#pragma unroll
            for (int j = 0; j < SLICE / 256; j++) {
                int e = base + j * 256 + tid;
                if (e < N_EDGES) {
                    int d = ep0[e].y;
                    if (d >= lo && d < hi2)
                        rank[e] = (unsigned short)atomicAdd(&cnt[(size_t)d * CPAD], 1);
                }
            }
        }
    }
    gg.sync();

    // ---- Phase C: per-chunk exclusive scan (blocks 0..195) + dinv
    if (blockIdx.x < NB_SCAN) {
        int g = (int)blockIdx.x * SCAN_B + tid;
        int vv = (g < N_NODES) ? cnt[(size_t)g * CPAD] : 0;
        if (g < N_NODES) dinv[g] = rsqrtf((float)(vv + 1));   // +1 self loop
        sb[tid] = vv;
        __syncthreads();
        for (int o = 1; o < SCAN_B; o <<= 1) {
            int add = (tid >= o) ? sb[tid - o] : 0;
            __syncthreads();
            sb[tid] += add;
            __syncthreads();
        }
        if (g < N_NODES) pre[g] = sb[tid] - vv;
        if (tid == SCAN_B - 1) bsum[blockIdx.x] = sb[tid];
    }
    gg.sync();

    // ---- bsum exclusive scan, once, kept in persistent LDS sx
    {
        int bv = (tid < NB_SCAN) ? bsum[tid] : 0;
        sb[tid] = bv;
        __syncthreads();
        for (int o = 1; o < 256; o <<= 1) {
            int a = (tid >= o) ? sb[tid - o] : 0;
            __syncthreads();
            sb[tid] += a;
            __syncthreads();
        }
        sx[tid] = sb[tid] - bv;
        __syncthreads();
    }

    // ---- Phase D: deterministic scatter (no atomics)
    for (int e = gi0; e < N_EDGES; e += nthr) {
        ushort2 sd = ep0[e];
        int d = sd.y;
        int p = pre[d] + sx[d >> 8] + (int)rank[e];
        int s = sd.x;
        ep[p] = make_int2(s, __float_as_int(dinv[s]));
    }
    gg.sync();

    const int wid = __builtin_amdgcn_readfirstlane(gi0 >> 6);
    const int nw  = nthr >> 6;                        // 2048 waves
    float wcol[HIDDEN];                               // reused across phases

    // ---- Phase E: layer 1  h1 = relu((A_norm x) W1 + b1)
    {
        int gsel = lane >> 2;                         // 16 groups of 4 lanes
        int c    = lane & 3;                          // 4 x uint4 = 64B row
        const uint4* x4 = (const uint4*)xb;
#pragma unroll
        for (int k = 0; k < IN_DIM; k++) wcol[k] = W1[k * 64 + lane];
        float bb = b1[lane];
        int v = wid;
        int e0 = 0, e1 = 0;
        float dv = 0.0f;
        uint4 hv = make_uint4(0, 0, 0, 0);
        int2 pr = make_int2(0, 0);
        if (v < N_NODES) {
            e0 = pre[v] + sx[v >> 8];
            e1 = (v + 1 < N_NODES) ? pre[v + 1] + sx[(v + 1) >> 8] : N_EDGES;
            dv = dinv[v];
            hv = x4[(size_t)v * 4 + c];
            if (lane < e1 - e0) pr = ep[e0 + lane];
        }
        while (v < N_NODES) {
            int vn = v + nw;
            int e0n = 0, e1n = 0;
            float dvn = 0.0f;
            uint4 hvn = make_uint4(0, 0, 0, 0);
            int2 prn = make_int2(0, 0);
            if (vn < N_NODES) {                       // prefetch next node
                e0n = pre[vn] + sx[vn >> 8];
                e1n = (vn + 1 < N_NODES) ? pre[vn + 1] + sx[(vn + 1) >> 8] : N_EDGES;
                dvn = dinv[vn];
                hvn = x4[(size_t)vn * 4 + c];
                if (lane < e1n - e0n) prn = ep[e0n + lane];
            }
            float sv = (gsel == 0) ? dv : 0.0f;       // self term once
            float acc[8];
            mul8(sv, hv, acc);
            agg32(e0, e1, pr, ep, x4, eb, lane, gsel, c, acc);
#pragma unroll
            for (int i = 0; i < 8; i++) {
                acc[i] += __shfl_xor(acc[i], 4);
                acc[i] += __shfl_xor(acc[i], 8);
                acc[i] += __shfl_xor(acc[i], 16);
                acc[i] += __shfl_xor(acc[i], 32);
            }
            if (lane < 4) {
                float4* qd = (float4*)(&sq[wav][lane * 8]);
                qd[0] = make_float4(dv * acc[0], dv * acc[1], dv * acc[2], dv * acc[3]);
                qd[1] = make_float4(dv * acc[4], dv * acc[5], dv * acc[6], dv * acc[7]);
            }
            float o0 = bb, o1 = 0.0f, o2 = 0.0f, o3 = 0.0f;
            const float4* q4 = (const float4*)(&sq[wav][0]);
#pragma unroll
            for (int k = 0; k < IN_DIM / 4; k++) {
                float4 tq = q4[k];
                o0 = fmaf(tq.x, wcol[4 * k + 0], o0);
                o1 = fmaf(tq.y, wcol[4 * k + 1], o1);
                o2 = fmaf(tq.z, wcol[4 * k + 2], o2);
                o3 = fmaf(tq.w, wcol[4 * k + 3], o3);
            }
            float o = (o0 + o1) + (o2 + o3);
            H[(size_t)v * 64 + lane] = f2bf(fmaxf(o, 0.0f));
            v = vn; e0 = e0n; e1 = e1n; dv = dvn; hv = hvn; pr = prn;
        }
    }
    gg.sync();

    // ---- Phase F: layer 2  h2 = relu((A_norm h1) W2 + b2)
    {
        int gsel = lane >> 3;                         // 8 groups of 8 lanes
        int c    = lane & 7;                          // 8 x uint4 = 128B row
        const uint4* g4 = (const uint4*)H;
#pragma unroll
        for (int k = 0; k < HIDDEN; k++) wcol[k] = W2[k * 64 + lane];
        float bb = b2[lane];
        int v = wid;
        int e0 = 0, e1 = 0;
        float dv = 0.0f;
        uint4 hv = make_uint4(0, 0, 0, 0);
        int2 pr = make_int2(0, 0);
        if (v < N_NODES) {
            e0 = pre[v] + sx[v >> 8];
            e1 = (v + 1 < N_NODES) ? pre[v + 1] + sx[(v + 1) >> 8] : N_EDGES;
            dv = dinv[v];
            hv = g4[(size_t)v * 8 + c];
            if (lane < e1 - e0) pr = ep[e0 + lane];
        }
        while (v < N_NODES) {
            int vn = v + nw;
            int e0n = 0, e1n = 0;
            float dvn = 0.0f;
            uint4 hvn = make_uint4(0, 0, 0, 0);
            int2 prn = make_int2(0, 0);
            if (vn < N_NODES) {
                e0n = pre[vn] + sx[vn >> 8];
                e1n = (vn + 1 < N_NODES) ? pre[vn + 1] + sx[(vn + 1) >> 8] : N_EDGES;
                dvn = dinv[vn];
                hvn = g4[(size_t)vn * 8 + c];
                if (lane < e1n - e0n) prn = ep[e0n + lane];
            }
            float sv = (gsel == 0) ? dv : 0.0f;
            float acc[8];
            mul8(sv, hv, acc);
            agg64(e0, e1, pr, ep, g4, eb, lane, gsel, c, acc);
#pragma unroll
            for (int i = 0; i < 8; i++) {
                acc[i] += __shfl_xor(acc[i], 8);
                acc[i] += __shfl_xor(acc[i], 16);
                acc[i] += __shfl_xor(acc[i], 32);
            }
            if (lane < 8) {
                float4* qd = (float4*)(&sq[wav][lane * 8]);
                qd[0] = make_float4(dv * acc[0], dv * acc[1], dv * acc[2], dv * acc[3]);
                qd[1] = make_float4(dv * acc[4], dv * acc[5], dv * acc[6], dv * acc[7]);
            }
            float o0 = bb, o1 = 0.0f, o2 = 0.0f, o3 = 0.0f;
            const float4* q4 = (const float4*)(&sq[wav][0]);
#pragma unroll
            for (int k = 0; k < HIDDEN / 4; k++) {
                float4 tq = q4[k];
                o0 = fmaf(tq.x, wcol[4 * k + 0], o0);
                o1 = fmaf(tq.y, wcol[4 * k + 1], o1);
                o2 = fmaf(tq.z, wcol[4 * k + 2], o2);
                o3 = fmaf(tq.w, wcol[4 * k + 3], o3);
            }
            float o = (o0 + o1) + (o2 + o3);
            G[(size_t)v * 64 + lane] = f2bf(fmaxf(o, 0.0f));
            v = vn; e0 = e0n; e1 = e1n; dv = dvn; hv = hvn; pr = prn;
        }
    }
    gg.sync();

    // ---- Phase G: heads  q = A_norm h2; mu|lv = q@[Wmu|Wlv]+b; z = mu+exp(.5lv)eps
    {
        int gsel = lane >> 3;
        int c    = lane & 7;
        int f    = lane & 31;
        bool hi  = lane >= 32;
        const uint4* g4 = (const uint4*)G;
#pragma unroll
        for (int k = 0; k < HIDDEN; k++)
            wcol[k] = hi ? Wlv[k * 32 + f] : Wmu[k * 32 + f];
        float bb = hi ? blv[f] : bmu[f];
        float* z  = outz;
        float* mu = outz + (size_t)N_NODES * Z_DIM;
        float* lv = outz + 2 * (size_t)N_NODES * Z_DIM;
        int v = wid;
        int e0 = 0, e1 = 0;
        float dv = 0.0f;
        uint4 hv = make_uint4(0, 0, 0, 0);
        int2 pr = make_int2(0, 0);
        if (v < N_NODES) {
            e0 = pre[v] + sx[v >> 8];
            e1 = (v + 1 < N_NODES) ? pre[v + 1] + sx[(v + 1) >> 8] : N_EDGES;
            dv = dinv[v];
            hv = g4[(size_t)v * 8 + c];
            if (lane < e1 - e0) pr = ep[e0 + lane];
        }
        while (v < N_NODES) {
            int vn = v + nw;
            int e0n = 0, e1n = 0;
            float dvn = 0.0f;
            uint4 hvn = make_uint4(0, 0, 0, 0);
            int2 prn = make_int2(0, 0);
            if (vn < N_NODES) {
                e0n = pre[vn] + sx[vn >> 8];
                e1n = (vn + 1 < N_NODES) ? pre[vn + 1] + sx[(vn + 1) >> 8] : N_EDGES;
                dvn = dinv[vn];
                hvn = g4[(size_t)vn * 8 + c];
                if (lane < e1n - e0n) prn = ep[e0n + lane];
            }
            float sv = (gsel == 0) ? dv : 0.0f;
            float acc[8];
            mul8(sv, hv, acc);
            agg64(e0, e1, pr, ep, g4, eb, lane, gsel, c, acc);
#pragma unroll
            for (int i = 0; i < 8; i++) {
                acc[i] += __shfl_xor(acc[i], 8);
                acc[i] += __shfl_xor(acc[i], 16);
                acc[i] += __shfl_xor(acc[i], 32);
            }
            if (lane < 8) {
                float4* qd = (float4*)(&sq[wav][lane * 8]);
                qd[0] = make_float4(dv * acc[0], dv * acc[1], dv * acc[2], dv * acc[3]);
                qd[1] = make_float4(dv * acc[4], dv * acc[5], dv * acc[6], dv * acc[7]);
            }
            float m0 = bb, m1 = 0.0f, m2 = 0.0f, m3 = 0.0f;
            const float4* q4 = (const float4*)(&sq[wav][0]);
#pragma unroll
            for (int k = 0; k < HIDDEN / 4; k++) {
                float4 tq = q4[k];
                m0 = fmaf(tq.x, wcol[4 * k + 0], m0);
                m1 = fmaf(tq.y, wcol[4 * k + 1], m1);
                m2 = fmaf(tq.z, wcol[4 * k + 2], m2);
                m3 = fmaf(tq.w, wcol[4 * k + 3], m3);
            }
            float m = (m0 + m1) + (m2 + m3);
            float ev = eps[(size_t)v * Z_DIM + f];
            float t  = expf(0.5f * m) * ev;
            float tlo = __shfl(t, lane | 32);
            size_t o = (size_t)v * Z_DIM + f;
            if (!hi) { mu[o] = m; z[o] = m + tlo; }
            else     { lv[o] = m; }
            v = vn; e0 = e0n; e1 = e1n; dv = dvn; hv = hvn; pr = prn;
        }
    }
}

// ---------------------------------------------------------------------------
extern "C" void kernel_launch(void* const* d_in, const int* in_sizes, int n_in,
                              void* d_out, int out_size, void* d_ws, size_t ws_size,
                              hipStream_t stream) {
    const float* x   = (const float*)d_in[0];
    const void*  ei  = d_in[1];
    const float* W1  = (const float*)d_in[2];
    const float* b1  = (const float*)d_in[3];
    const float* W2  = (const float*)d_in[4];
    const float* b2  = (const float*)d_in[5];
    const float* Wmu = (const float*)d_in[6];
    const float* bmu = (const float*)d_in[7];
    const float* Wlv = (const float*)d_in[8];
    const float* blv = (const float*)d_in[9];
    const float* eps = (const float*)d_in[10];
    float* out = (float*)d_out;
    (void)in_sizes; (void)n_in; (void)out_size; (void)ws_size;

    char* ws = (char*)d_ws;
    size_t off = 0;
    auto alloc = [&](size_t bytes) -> void* {
        void* p = ws + off;
        off += (bytes + 255) & ~(size_t)255;
        return p;
    };
    int2*           ep     = (int2*)alloc(sizeof(int2) * N_EDGES);       // 6.4 MB
    ushort2*        ep0    = (ushort2*)alloc(sizeof(ushort2) * N_EDGES); // 3.2 MB
    unsigned short* rank   = (unsigned short*)alloc(sizeof(short) * N_EDGES);  // 1.6 MB
    int*            pre    = (int*)alloc(sizeof(int) * (N_NODES + 1));
    int*            cnt    = (int*)alloc(sizeof(int) * (size_t)N_NODES * CPAD); // 3.2 MB
    float*          dinv   = (float*)alloc(sizeof(float) * N_NODES);
    int*            bsum   = (int*)alloc(sizeof(int) * 256);
    unsigned short* xb     = (unsigned short*)alloc(sizeof(short) * (size_t)N_NODES * IN_DIM);  // 3.2 MB
    unsigned short* G      = (unsigned short*)alloc(sizeof(short) * (size_t)N_NODES * HIDDEN);  // 6.4 MB
    unsigned short* H      = (unsigned short*)alloc(sizeof(short) * (size_t)N_NODES * HIDDEN);  // 6.4 MB

    void* kargs[] = {
        (void*)&x, (void*)&ei,
        (void*)&W1, (void*)&b1, (void*)&W2, (void*)&b2,
        (void*)&Wmu, (void*)&bmu, (void*)&Wlv, (void*)&blv,
        (void*)&eps, (void*)&out,
        (void*)&ep, (void*)&ep0, (void*)&rank, (void*)&pre,
        (void*)&cnt, (void*)&dinv, (void*)&bsum, (void*)&xb,
        (void*)&G, (void*)&H
    };
    hipLaunchCooperativeKernel((void*)mega_kernel, dim3(GRID), dim3(256),
                               kargs, 0, stream);
}

// Round 7
// 424.991 us; speedup vs baseline: 1.5576x; 1.5576x over previous
//
#include <hip/hip_runtime.h>
#include <math.h>

#define N_NODES 50000
#define N_EDGES 800000
#define IN_DIM 32
#define HIDDEN 64
#define Z_DIM 32
#define SCAN_B 256
#define NB_SCAN ((N_NODES + SCAN_B - 1) / SCAN_B)   // 196
#define N_XCD 8
#define NPX ((N_NODES + N_XCD - 1) / N_XCD)         // 6250 nodes per XCD range
#define SLICE 2048
#define N_SLICE ((N_EDGES + SLICE - 1) / SLICE)     // 391
#define SCAT_B (N_SLICE * N_XCD)                    // 3128 hist blocks
#define FB 2048                                     // 8192 waves for node kernels
#define CPAD 16                                     // cnt stride: 1 line/node

// bf16 (stored as ushort) <-> f32 helpers, RNE
__device__ __forceinline__ unsigned short f2bf(float f) {
    unsigned int u = __float_as_uint(f);
    u += 0x7fffu + ((u >> 16) & 1u);
    return (unsigned short)(u >> 16);
}

// wave-local edge dtype detect: int64 LE values < 2^31 have all-zero odd words.
__device__ __forceinline__ int detect64(const int* raw) {
    int lane = threadIdx.x & 63;
    int odd = raw[2 * lane + 1];
    unsigned long long b = __ballot(odd != 0);
    return (b == 0ULL) ? 1 : 0;
}

// 8 bf16 (packed in uint4) FMA into acc[8]
__device__ __forceinline__ void fma8(float w, uint4 f, float acc[8]) {
    acc[0] = fmaf(w, __uint_as_float(f.x << 16),         acc[0]);
    acc[1] = fmaf(w, __uint_as_float(f.x & 0xffff0000u), acc[1]);
    acc[2] = fmaf(w, __uint_as_float(f.y << 16),         acc[2]);
    acc[3] = fmaf(w, __uint_as_float(f.y & 0xffff0000u), acc[3]);
    acc[4] = fmaf(w, __uint_as_float(f.z << 16),         acc[4]);
    acc[5] = fmaf(w, __uint_as_float(f.z & 0xffff0000u), acc[5]);
    acc[6] = fmaf(w, __uint_as_float(f.w << 16),         acc[6]);
    acc[7] = fmaf(w, __uint_as_float(f.w & 0xffff0000u), acc[7]);
}
__device__ __forceinline__ void mul8(float w, uint4 f, float acc[8]) {
    acc[0] = w * __uint_as_float(f.x << 16);
    acc[1] = w * __uint_as_float(f.x & 0xffff0000u);
    acc[2] = w * __uint_as_float(f.y << 16);
    acc[3] = w * __uint_as_float(f.y & 0xffff0000u);
    acc[4] = w * __uint_as_float(f.z << 16);
    acc[5] = w * __uint_as_float(f.z & 0xffff0000u);
    acc[6] = w * __uint_as_float(f.w << 16);
    acc[7] = w * __uint_as_float(f.w & 0xffff0000u);
}

// ---------------------------------------------------------------------------
// prep_a: pure streaming. x->bf16 convert; edge compaction to ushort2 (node
// ids < 2^16); cnt zeroing folded in (saves the memset dispatch).
__global__ void prep_a_kernel(const float* __restrict__ x, unsigned short* __restrict__ xb,
                              const void* __restrict__ raw, ushort2* __restrict__ ep0,
                              int* __restrict__ cnt) {
    int is64 = detect64((const int*)raw);
    int i = blockIdx.x * 256 + threadIdx.x;
    if (i < N_NODES * IN_DIM) xb[i] = f2bf(x[i]);
    if (i < N_NODES * CPAD) cnt[i] = 0;
    if (i < N_EDGES) {
        int s, d;
        if (is64) {
            s = (int)((const long long*)raw)[i];
            d = (int)((const long long*)raw)[N_EDGES + i];
        } else {
            s = ((const int*)raw)[i];
            d = ((const int*)raw)[N_EDGES + i];
        }
        ep0[i] = make_ushort2((unsigned short)s, (unsigned short)d);
    }
}

// ---------------------------------------------------------------------------
// hist: XCD-partitioned degree count + per-edge rank capture.
__global__ __launch_bounds__(256) void hist_kernel(const ushort2* __restrict__ ep0,
                                                   int* __restrict__ cnt,
                                                   unsigned short* __restrict__ rank) {
    int xcd = blockIdx.x % N_XCD;
    int sl  = blockIdx.x / N_XCD;
    int lo  = xcd * NPX, hi = lo + NPX;
    int base = sl * SLICE;
#pragma unroll
    for (int j = 0; j < SLICE / 256; j++) {
        int e = base + j * 256 + threadIdx.x;
        if (e < N_EDGES) {
            int d = ep0[e].y;
            if (d >= lo && d < hi)
                rank[e] = (unsigned short)atomicAdd(&cnt[(size_t)d * CPAD], 1);
        }
    }
}

// ---------------------------------------------------------------------------
// scan1: block-local exclusive scan of cnt (padded) -> pre, block sums, dinv.
__global__ void scan1_kernel(const int* __restrict__ cnt, int* __restrict__ pre,
                             int* __restrict__ bsum, float* __restrict__ dinv) {
    __shared__ int s[SCAN_B];
    int t = threadIdx.x;
    int g = blockIdx.x * SCAN_B + t;
    int v = (g < N_NODES) ? cnt[(size_t)g * CPAD] : 0;
    if (g < N_NODES) dinv[g] = rsqrtf((float)(v + 1));   // +1 self loop
    s[t] = v;
    __syncthreads();
    for (int o = 1; o < SCAN_B; o <<= 1) {
        int add = (t >= o) ? s[t - o] : 0;
        __syncthreads();
        s[t] += add;
        __syncthreads();
    }
    if (g < N_NODES) pre[g] = s[t] - v;
    if (t == SCAN_B - 1) bsum[blockIdx.x] = s[t];
}

// Block-start prologue: redundant LDS exclusive-scan of the 196 bsums.
// rowptr(v) = pre[v] + sx[v>>8].  (First __syncthreads also fences any LDS
// preload issued before this macro.)
#define BSUM_SCAN_PROLOGUE(bsum, sb, sx)                                    \
    {                                                                       \
        int t_ = threadIdx.x;                                               \
        int bv_ = (t_ < NB_SCAN) ? bsum[t_] : 0;                            \
        sb[t_] = bv_;                                                       \
        __syncthreads();                                                    \
        for (int o_ = 1; o_ < 256; o_ <<= 1) {                              \
            int a_ = (t_ >= o_) ? sb[t_ - o_] : 0;                          \
            __syncthreads();                                                \
            sb[t_] += a_;                                                   \
            __syncthreads();                                                \
        }                                                                   \
        sx[t_] = sb[t_] - bv_;                                              \
        __syncthreads();                                                    \
    }

// ---------------------------------------------------------------------------
// Deterministic scatter: single pass, no atomics. Slot = rowptr[dst] + rank.
__global__ __launch_bounds__(256) void scatter_kernel(
        const ushort2* __restrict__ ep0, const unsigned short* __restrict__ rank,
        const int* __restrict__ pre, const int* __restrict__ bsum,
        const float* __restrict__ dinv, int2* __restrict__ ep) {
    __shared__ int sb[256];
    __shared__ int sx[256];
    BSUM_SCAN_PROLOGUE(bsum, sb, sx)
    int base = blockIdx.x * SLICE;
#pragma unroll
    for (int j = 0; j < SLICE / 256; j++) {
        int e = base + j * 256 + threadIdx.x;
        if (e < N_EDGES) {
            ushort2 sd = ep0[e];
            int d = sd.y;
            int p = pre[d] + sx[d >> 8] + (int)rank[e];
            int s = sd.x;
            ep[p] = make_int2(s, __float_as_int(dinv[s]));
        }
    }
}

// ---------------------------------------------------------------------------
// 64-wide aggregation. Edge batch staged into the wave's LDS slot; uint4
// feature gathers (8 lanes x 16B = 128B row, 8 edges per load instruction).
__device__ __forceinline__ void agg64(int e0, int e1, int2 pr,
                                      const int2* __restrict__ ep,
                                      const uint4* __restrict__ g4,
                                      int2* eb, int lane, int gsel, int c,
                                      float acc[8]) {
    for (int b0 = e0; b0 < e1; b0 += 64) {
        int cnt = e1 - b0; cnt = cnt > 64 ? 64 : cnt;        // uniform
        eb[lane] = pr;                                       // stage batch
        for (int j = 0; j < cnt; j += 16) {
            int2 ew0 = eb[j + gsel];                         // gsel in 0..7
            int2 ew1 = eb[j + 8 + gsel];
            uint4 f0 = g4[(size_t)ew0.x * 8 + c];
            uint4 f1 = g4[(size_t)ew1.x * 8 + c];
            fma8(__int_as_float(ew0.y), f0, acc);
            fma8(__int_as_float(ew1.y), f1, acc);
        }
        if (b0 + 64 < e1) {                                  // rare extra batch
            pr = make_int2(0, 0);
            int idx = b0 + 64 + lane;
            if (idx < e1) pr = ep[idx];
        }
    }
}

// 32-wide aggregation: 4 lanes x 16B cover one 64B row -> 16 edges per load.
__device__ __forceinline__ void agg32(int e0, int e1, int2 pr,
                                      const int2* __restrict__ ep,
                                      const uint4* __restrict__ x4,
                                      int2* eb, int lane, int gsel, int c,
                                      float acc[8]) {
    for (int b0 = e0; b0 < e1; b0 += 64) {
        int cnt = e1 - b0; cnt = cnt > 64 ? 64 : cnt;
        eb[lane] = pr;
        for (int j = 0; j < cnt; j += 32) {
            int2 ew0 = eb[j + gsel];                         // gsel in 0..15
            int2 ew1 = eb[j + 16 + gsel];
            uint4 f0 = x4[(size_t)ew0.x * 4 + c];
            uint4 f1 = x4[(size_t)ew1.x * 4 + c];
            fma8(__int_as_float(ew0.y), f0, acc);
            fma8(__int_as_float(ew1.y), f1, acc);
        }
        if (b0 + 64 < e1) {
            pr = make_int2(0, 0);
            int idx = b0 + 64 + lane;
            if (idx < e1) pr = ep[idx];
        }
    }
}

// ---------------------------------------------------------------------------
// Fused layer 1: q = normAgg(xb) [32-wide], out = relu(q @ W1 + b1).
// W lives in LDS (col-major w[k*64+lane], conflict-free b32 reads), dense
// apply batched over 4 nodes so W is read once per 4 nodes. NO per-lane W
// array -> no spill (the wcol[64] register array spilled to scratch at every
// launch-bounds setting; scratch reloads were ~800MB/layer and dominated).
__global__ __launch_bounds__(256) void fused_layer32_kernel(
        const int* __restrict__ pre, const int* __restrict__ bsum,
        const int2* __restrict__ ep, const float* __restrict__ dinv,
        const unsigned short* __restrict__ xb,
        const float* __restrict__ W1, const float* __restrict__ b1,
        unsigned short* __restrict__ out) {
    __shared__ int sb[256];
    __shared__ int sx[256];
    __shared__ int2 ebuf[4][64];
    __shared__ float sq[4][4][IN_DIM];
    __shared__ float wlds[IN_DIM * 64];
    for (int i = threadIdx.x; i < IN_DIM * 64; i += 256) wlds[i] = W1[i];
    BSUM_SCAN_PROLOGUE(bsum, sb, sx)
    int lane = threadIdx.x & 63;
    int wav  = threadIdx.x >> 6;
    int gsel = lane >> 2;                                    // 16 groups
    int c    = lane & 3;                                     // 4 x uint4 = 64B row
    const uint4* x4 = (const uint4*)xb;
    int2* eb = &ebuf[wav][0];
    float bb = b1[lane];
    int wid = __builtin_amdgcn_readfirstlane((int)((blockIdx.x * blockDim.x + threadIdx.x) >> 6));
    int nw  = (gridDim.x * blockDim.x) >> 6;
    int v = wid;
    if (v >= N_NODES) return;
    int e0 = pre[v] + sx[v >> 8];
    int e1 = (v + 1 < N_NODES) ? pre[v + 1] + sx[(v + 1) >> 8] : N_EDGES;
    float dv = dinv[v];
    uint4 hv = x4[(size_t)v * 4 + c];
    int2 pr = make_int2(0, 0);
    if (lane < e1 - e0) pr = ep[e0 + lane];
    int nb = 0, vbase = v;
    while (v < N_NODES) {
        int vn = v + nw;
        int e0n = 0, e1n = 0;
        float dvn = 0.0f;
        uint4 hvn = make_uint4(0, 0, 0, 0);
        int2 prn = make_int2(0, 0);
        if (vn < N_NODES) {                                  // prefetch next node
            e0n = pre[vn] + sx[vn >> 8];
            e1n = (vn + 1 < N_NODES) ? pre[vn + 1] + sx[(vn + 1) >> 8] : N_EDGES;
            dvn = dinv[vn];
            hvn = x4[(size_t)vn * 4 + c];
            if (lane < e1n - e0n) prn = ep[e0n + lane];
        }
        float sv = (gsel == 0) ? dv : 0.0f;                  // self term once
        float acc[8];
        mul8(sv, hv, acc);
        agg32(e0, e1, pr, ep, x4, eb, lane, gsel, c, acc);
#pragma unroll
        for (int i = 0; i < 8; i++) {
            acc[i] += __shfl_xor(acc[i], 4);
            acc[i] += __shfl_xor(acc[i], 8);
            acc[i] += __shfl_xor(acc[i], 16);
            acc[i] += __shfl_xor(acc[i], 32);
        }
        if (lane < 4) {
            float4* qd = (float4*)(&sq[wav][nb][lane * 8]);
            qd[0] = make_float4(dv * acc[0], dv * acc[1], dv * acc[2], dv * acc[3]);
            qd[1] = make_float4(dv * acc[4], dv * acc[5], dv * acc[6], dv * acc[7]);
        }
        nb++;
        if (nb == 4 || vn >= N_NODES) {                      // dense apply, 4 nodes
            float o0 = bb, o1 = bb, o2 = bb, o3 = bb;
#pragma unroll
            for (int k4 = 0; k4 < IN_DIM / 4; k4++) {
                float4 q0 = *(const float4*)(&sq[wav][0][k4 * 4]);
                float4 q1 = *(const float4*)(&sq[wav][1][k4 * 4]);
                float4 q2 = *(const float4*)(&sq[wav][2][k4 * 4]);
                float4 q3 = *(const float4*)(&sq[wav][3][k4 * 4]);
                float w0 = wlds[(k4 * 4 + 0) * 64 + lane];
                float w1 = wlds[(k4 * 4 + 1) * 64 + lane];
                float w2 = wlds[(k4 * 4 + 2) * 64 + lane];
                float w3 = wlds[(k4 * 4 + 3) * 64 + lane];
                o0 = fmaf(q0.x, w0, o0); o0 = fmaf(q0.y, w1, o0);
                o0 = fmaf(q0.z, w2, o0); o0 = fmaf(q0.w, w3, o0);
                o1 = fmaf(q1.x, w0, o1); o1 = fmaf(q1.y, w1, o1);
                o1 = fmaf(q1.z, w2, o1); o1 = fmaf(q1.w, w3, o1);
                o2 = fmaf(q2.x, w0, o2); o2 = fmaf(q2.y, w1, o2);
                o2 = fmaf(q2.z, w2, o2); o2 = fmaf(q2.w, w3, o2);
                o3 = fmaf(q3.x, w0, o3); o3 = fmaf(q3.y, w1, o3);
                o3 = fmaf(q3.z, w2, o3); o3 = fmaf(q3.w, w3, o3);
            }
            out[(size_t)vbase * 64 + lane] = f2bf(fmaxf(o0, 0.0f));
            if (nb > 1) out[(size_t)(vbase + nw) * 64 + lane] = f2bf(fmaxf(o1, 0.0f));
            if (nb > 2) out[(size_t)(vbase + 2 * nw) * 64 + lane] = f2bf(fmaxf(o2, 0.0f));
            if (nb > 3) out[(size_t)(vbase + 3 * nw) * 64 + lane] = f2bf(fmaxf(o3, 0.0f));
            nb = 0; vbase = vn;
        }
        v = vn; e0 = e0n; e1 = e1n; dv = dvn; hv = hvn; pr = prn;
    }
}

// Fused layer 2: q = normAgg(g) [64-wide], out = relu(q @ W + b).
__global__ __launch_bounds__(256) void fused_layer64_kernel(
        const int* __restrict__ pre, const int* __restrict__ bsum,
        const int2* __restrict__ ep, const float* __restrict__ dinv,
        const unsigned short* __restrict__ g,
        const float* __restrict__ W, const float* __restrict__ bias,
        unsigned short* __restrict__ out) {
    __shared__ int sb[256];
    __shared__ int sx[256];
    __shared__ int2 ebuf[4][64];
    __shared__ float sq[4][4][HIDDEN];
    __shared__ float wlds[HIDDEN * 64];
    for (int i = threadIdx.x; i < HIDDEN * 64; i += 256) wlds[i] = W[i];
    BSUM_SCAN_PROLOGUE(bsum, sb, sx)
    int lane = threadIdx.x & 63;
    int wav  = threadIdx.x >> 6;
    int gsel = lane >> 3;                                    // 8 groups
    int c    = lane & 7;                                     // 8 x uint4 = 128B row
    const uint4* g4 = (const uint4*)g;
    int2* eb = &ebuf[wav][0];
    float bb = bias[lane];
    int wid = __builtin_amdgcn_readfirstlane((int)((blockIdx.x * blockDim.x + threadIdx.x) >> 6));
    int nw  = (gridDim.x * blockDim.x) >> 6;
    int v = wid;
    if (v >= N_NODES) return;
    int e0 = pre[v] + sx[v >> 8];
    int e1 = (v + 1 < N_NODES) ? pre[v + 1] + sx[(v + 1) >> 8] : N_EDGES;
    float dv = dinv[v];
    uint4 hv = g4[(size_t)v * 8 + c];
    int2 pr = make_int2(0, 0);
    if (lane < e1 - e0) pr = ep[e0 + lane];
    int nb = 0, vbase = v;
    while (v < N_NODES) {
        int vn = v + nw;
        int e0n = 0, e1n = 0;
        float dvn = 0.0f;
        uint4 hvn = make_uint4(0, 0, 0, 0);
        int2 prn = make_int2(0, 0);
        if (vn < N_NODES) {
            e0n = pre[vn] + sx[vn >> 8];
            e1n = (vn + 1 < N_NODES) ? pre[vn + 1] + sx[(vn + 1) >> 8] : N_EDGES;
            dvn = dinv[vn];
            hvn = g4[(size_t)vn * 8 + c];
            if (lane < e1n - e0n) prn = ep[e0n + lane];
        }
        float sv = (gsel == 0) ? dv : 0.0f;
        float acc[8];
        mul8(sv, hv, acc);
        agg64(e0, e1, pr, ep, g4, eb, lane, gsel, c, acc);
#pragma unroll
        for (int i = 0; i < 8; i++) {
            acc[i] += __shfl_xor(acc[i], 8);
            acc[i] += __shfl_xor(acc[i], 16);
            acc[i] += __shfl_xor(acc[i], 32);
        }
        if (lane < 8) {
            float4* qd = (float4*)(&sq[wav][nb][lane * 8]);
            qd[0] = make_float4(dv * acc[0], dv * acc[1], dv * acc[2], dv * acc[3]);
            qd[1] = make_float4(dv * acc[4], dv * acc[5], dv * acc[6], dv * acc[7]);
        }
        nb++;
        if (nb == 4 || vn >= N_NODES) {
            float o0 = bb, o1 = bb, o2 = bb, o3 = bb;
#pragma unroll
            for (int k4 = 0; k4 < HIDDEN / 4; k4++) {
                float4 q0 = *(const float4*)(&sq[wav][0][k4 * 4]);
                float4 q1 = *(const float4*)(&sq[wav][1][k4 * 4]);
                float4 q2 = *(const float4*)(&sq[wav][2][k4 * 4]);
                float4 q3 = *(const float4*)(&sq[wav][3][k4 * 4]);
                float w0 = wlds[(k4 * 4 + 0) * 64 + lane];
                float w1 = wlds[(k4 * 4 + 1) * 64 + lane];
                float w2 = wlds[(k4 * 4 + 2) * 64 + lane];
                float w3 = wlds[(k4 * 4 + 3) * 64 + lane];
                o0 = fmaf(q0.x, w0, o0); o0 = fmaf(q0.y, w1, o0);
                o0 = fmaf(q0.z, w2, o0); o0 = fmaf(q0.w, w3, o0);
                o1 = fmaf(q1.x, w0, o1); o1 = fmaf(q1.y, w1, o1);
                o1 = fmaf(q1.z, w2, o1); o1 = fmaf(q1.w, w3, o1);
                o2 = fmaf(q2.x, w0, o2); o2 = fmaf(q2.y, w1, o2);
                o2 = fmaf(q2.z, w2, o2); o2 = fmaf(q2.w, w3, o2);
                o3 = fmaf(q3.x, w0, o3); o3 = fmaf(q3.y, w1, o3);
                o3 = fmaf(q3.z, w2, o3); o3 = fmaf(q3.w, w3, o3);
            }
            out[(size_t)vbase * 64 + lane] = f2bf(fmaxf(o0, 0.0f));
            if (nb > 1) out[(size_t)(vbase + nw) * 64 + lane] = f2bf(fmaxf(o1, 0.0f));
            if (nb > 2) out[(size_t)(vbase + 2 * nw) * 64 + lane] = f2bf(fmaxf(o2, 0.0f));
            if (nb > 3) out[(size_t)(vbase + 3 * nw) * 64 + lane] = f2bf(fmaxf(o3, 0.0f));
            nb = 0; vbase = vn;
        }
        v = vn; e0 = e0n; e1 = e1n; dv = dvn; hv = hvn; pr = prn;
    }
}

// Fused heads: q = normAgg(h2); mu|lv = q@[Wmu|Wlv]+b; z = mu + exp(.5 lv)*eps.
__global__ __launch_bounds__(256) void fused_head_kernel(
        const int* __restrict__ pre, const int* __restrict__ bsum,
        const int2* __restrict__ ep, const float* __restrict__ dinv,
        const unsigned short* __restrict__ g,
        const float* __restrict__ Wmu, const float* __restrict__ Wlv,
        const float* __restrict__ bmu, const float* __restrict__ blv,
        const float* __restrict__ eps, float* __restrict__ outz) {
    __shared__ int sb[256];
    __shared__ int sx[256];
    __shared__ int2 ebuf[4][64];
    __shared__ float sq[4][4][HIDDEN];
    __shared__ float wlds[HIDDEN * 64];
    for (int i = threadIdx.x; i < HIDDEN * 64; i += 256) {
        int k = i >> 6, col = i & 63;
        wlds[i] = (col < 32) ? Wmu[k * 32 + col] : Wlv[k * 32 + (col - 32)];
    }
    BSUM_SCAN_PROLOGUE(bsum, sb, sx)
    int lane = threadIdx.x & 63;
    int wav  = threadIdx.x >> 6;
    int gsel = lane >> 3;
    int c    = lane & 7;
    int f = lane & 31;
    bool hi = lane >= 32;
    const uint4* g4 = (const uint4*)g;
    int2* eb = &ebuf[wav][0];
    float bb = hi ? blv[f] : bmu[f];
    float* z  = outz;
    float* mu = outz + (size_t)N_NODES * Z_DIM;
    float* lv = outz + 2 * (size_t)N_NODES * Z_DIM;
    int wid = __builtin_amdgcn_readfirstlane((int)((blockIdx.x * blockDim.x + threadIdx.x) >> 6));
    int nw  = (gridDim.x * blockDim.x) >> 6;
    int v = wid;
    if (v >= N_NODES) return;
    int e0 = pre[v] + sx[v >> 8];
    int e1 = (v + 1 < N_NODES) ? pre[v + 1] + sx[(v + 1) >> 8] : N_EDGES;
    float dv = dinv[v];
    uint4 hv = g4[(size_t)v * 8 + c];
    int2 pr = make_int2(0, 0);
    if (lane < e1 - e0) pr = ep[e0 + lane];
    int nb = 0, vbase = v;
    while (v < N_NODES) {
        int vn = v + nw;
        int e0n = 0, e1n = 0;
        float dvn = 0.0f;
        uint4 hvn = make_uint4(0, 0, 0, 0);
        int2 prn = make_int2(0, 0);
        if (vn < N_NODES) {
            e0n = pre[vn] + sx[vn >> 8];
            e1n = (vn + 1 < N_NODES) ? pre[vn + 1] + sx[(vn + 1) >> 8] : N_EDGES;
            dvn = dinv[vn];
            hvn = g4[(size_t)vn * 8 + c];
            if (lane < e1n - e0n) prn = ep[e0n + lane];
        }
        float sv = (gsel == 0) ? dv : 0.0f;
        float acc[8];
        mul8(sv, hv, acc);
        agg64(e0, e1, pr, ep, g4, eb, lane, gsel, c, acc);
#pragma unroll
        for (int i = 0; i < 8; i++) {
            acc[i] += __shfl_xor(acc[i], 8);
            acc[i] += __shfl_xor(acc[i], 16);
            acc[i] += __shfl_xor(acc[i], 32);
        }
        if (lane < 8) {
            float4* qd = (float4*)(&sq[wav][nb][lane * 8]);
            qd[0] = make_float4(dv * acc[0], dv * acc[1], dv * acc[2], dv * acc[3]);
            qd[1] = make_float4(dv * acc[4], dv * acc[5], dv * acc[6], dv * acc[7]);
        }
        nb++;
        if (nb == 4 || vn >= N_NODES) {
            float o0 = bb, o1 = bb, o2 = bb, o3 = bb;
#pragma unroll
            for (int k4 = 0; k4 < HIDDEN / 4; k4++) {
                float4 q0 = *(const float4*)(&sq[wav][0][k4 * 4]);
                float4 q1 = *(const float4*)(&sq[wav][1][k4 * 4]);
                float4 q2 = *(const float4*)(&sq[wav][2][k4 * 4]);
                float4 q3 = *(const float4*)(&sq[wav][3][k4 * 4]);
                float w0 = wlds[(k4 * 4 + 0) * 64 + lane];
                float w1 = wlds[(k4 * 4 + 1) * 64 + lane];
                float w2 = wlds[(k4 * 4 + 2) * 64 + lane];
                float w3 = wlds[(k4 * 4 + 3) * 64 + lane];
                o0 = fmaf(q0.x, w0, o0); o0 = fmaf(q0.y, w1, o0);
                o0 = fmaf(q0.z, w2, o0); o0 = fmaf(q0.w, w3, o0);
                o1 = fmaf(q1.x, w0, o1); o1 = fmaf(q1.y, w1, o1);
                o1 = fmaf(q1.z, w2, o1); o1 = fmaf(q1.w, w3, o1);
                o2 = fmaf(q2.x, w0, o2); o2 = fmaf(q2.y, w1, o2);
                o2 = fmaf(q2.z, w2, o2); o2 = fmaf(q2.w, w3, o2);
                o3 = fmaf(q3.x, w0, o3); o3 = fmaf(q3.y, w1, o3);
                o3 = fmaf(q3.z, w2, o3); o3 = fmaf(q3.w, w3, o3);
            }
#pragma unroll
            for (int n = 0; n < 4; n++) {
                if (n < nb) {
                    int vv = vbase + n * nw;
                    float m = (n == 0) ? o0 : (n == 1) ? o1 : (n == 2) ? o2 : o3;
                    float ev = eps[(size_t)vv * Z_DIM + f];
                    float t  = expf(0.5f * m) * ev;
                    float tlo = __shfl(t, lane | 32);
                    size_t o = (size_t)vv * Z_DIM + f;
                    if (!hi) { mu[o] = m; z[o] = m + tlo; }
                    else     { lv[o] = m; }
                }
            }
            nb = 0; vbase = vn;
        }
        v = vn; e0 = e0n; e1 = e1n; dv = dvn; hv = hvn; pr = prn;
    }
}

// ---------------------------------------------------------------------------
extern "C" void kernel_launch(void* const* d_in, const int* in_sizes, int n_in,
                              void* d_out, int out_size, void* d_ws, size_t ws_size,
                              hipStream_t stream) {
    const float* x   = (const float*)d_in[0];
    const void*  ei  = d_in[1];
    const float* W1  = (const float*)d_in[2];
    const float* b1  = (const float*)d_in[3];
    const float* W2  = (const float*)d_in[4];
    const float* b2  = (const float*)d_in[5];
    const float* Wmu = (const float*)d_in[6];
    const float* bmu = (const float*)d_in[7];
    const float* Wlv = (const float*)d_in[8];
    const float* blv = (const float*)d_in[9];
    const float* eps = (const float*)d_in[10];
    float* out = (float*)d_out;
    (void)in_sizes; (void)n_in; (void)out_size; (void)ws_size;

    char* ws = (char*)d_ws;
    size_t off = 0;
    auto alloc = [&](size_t bytes) -> void* {
        void* p = ws + off;
        off += (bytes + 255) & ~(size_t)255;
        return p;
    };
    int2*           ep     = (int2*)alloc(sizeof(int2) * N_EDGES);       // 6.4 MB
    ushort2*        ep0    = (ushort2*)alloc(sizeof(ushort2) * N_EDGES); // 3.2 MB
    unsigned short* rank   = (unsigned short*)alloc(sizeof(short) * N_EDGES);  // 1.6 MB
    int*            pre    = (int*)alloc(sizeof(int) * (N_NODES + 1));
    int*            cnt    = (int*)alloc(sizeof(int) * (size_t)N_NODES * CPAD); // 3.2 MB
    float*          dinv   = (float*)alloc(sizeof(float) * N_NODES);
    int*            bsum   = (int*)alloc(sizeof(int) * 256);
    unsigned short* xb     = (unsigned short*)alloc(sizeof(short) * (size_t)N_NODES * IN_DIM);  // 3.2 MB
    unsigned short* G      = (unsigned short*)alloc(sizeof(short) * (size_t)N_NODES * HIDDEN);  // 6.4 MB
    unsigned short* H      = (unsigned short*)alloc(sizeof(short) * (size_t)N_NODES * HIDDEN);  // 6.4 MB

    prep_a_kernel<<<(N_NODES * IN_DIM + 255) / 256, 256, 0, stream>>>(x, xb, ei, ep0, cnt);
    hist_kernel<<<SCAT_B, 256, 0, stream>>>(ep0, cnt, rank);
    scan1_kernel<<<NB_SCAN, SCAN_B, 0, stream>>>(cnt, pre, bsum, dinv);
    scatter_kernel<<<N_SLICE, 256, 0, stream>>>(ep0, rank, pre, bsum, dinv, ep);
    // Layer 1: h1 = relu((A_norm x) W1 + b1)   [agg on 32-wide input]
    fused_layer32_kernel<<<FB, 256, 0, stream>>>(pre, bsum, ep, dinv, xb, W1, b1, H);
    // Layer 2: h2 = relu((A_norm h1) W2 + b2)
    fused_layer64_kernel<<<FB, 256, 0, stream>>>(pre, bsum, ep, dinv, H, W2, b2, G);
    // Heads: q = A_norm h2 ; mu = qWmu+bmu ; lv = qWlv+blv ; z = mu+exp(.5lv)eps
    fused_head_kernel<<<FB, 256, 0, stream>>>(pre, bsum, ep, dinv, G, Wmu, Wlv, bmu, blv, eps, out);
}

// Round 8
// 360.443 us; speedup vs baseline: 1.8365x; 1.1791x over previous
//
#include <hip/hip_runtime.h>
#include <math.h>

#define N_NODES 50000
#define N_EDGES 800000
#define IN_DIM 32
#define HIDDEN 64
#define Z_DIM 32
#define SCAN_B 256
#define NB_SCAN ((N_NODES + SCAN_B - 1) / SCAN_B)   // 196
#define N_XCD 8
#define NPX ((N_NODES + N_XCD - 1) / N_XCD)         // 6250 nodes per XCD range
#define SLICE 2048
#define N_SLICE ((N_EDGES + SLICE - 1) / SLICE)     // 391
#define SCAT_B (N_SLICE * N_XCD)                    // 3128 hist blocks
#define CPAD 16                                     // cnt stride: 1 line/node

// Node kernels: one node per lane-group, exactly one pass.
#define NPW64 8                                     // nodes/wave, 8-lane groups
#define NPB64 (4 * NPW64)                           // 32 nodes/block
#define FB64 ((N_NODES + NPB64 - 1) / NPB64)        // 1563 blocks
#define NPW32 16                                    // nodes/wave, 4-lane groups
#define NPB32 (4 * NPW32)                           // 64 nodes/block
#define FB32 ((N_NODES + NPB32 - 1) / NPB32)        // 782 blocks

// bf16 (stored as ushort) <-> f32 helpers, RNE
__device__ __forceinline__ unsigned short f2bf(float f) {
    unsigned int u = __float_as_uint(f);
    u += 0x7fffu + ((u >> 16) & 1u);
    return (unsigned short)(u >> 16);
}

// wave-local edge dtype detect: int64 LE values < 2^31 have all-zero odd words.
__device__ __forceinline__ int detect64(const int* raw) {
    int lane = threadIdx.x & 63;
    int odd = raw[2 * lane + 1];
    unsigned long long b = __ballot(odd != 0);
    return (b == 0ULL) ? 1 : 0;
}

// 8 bf16 (packed in uint4) FMA into acc[8]
__device__ __forceinline__ void fma8(float w, uint4 f, float acc[8]) {
    acc[0] = fmaf(w, __uint_as_float(f.x << 16),         acc[0]);
    acc[1] = fmaf(w, __uint_as_float(f.x & 0xffff0000u), acc[1]);
    acc[2] = fmaf(w, __uint_as_float(f.y << 16),         acc[2]);
    acc[3] = fmaf(w, __uint_as_float(f.y & 0xffff0000u), acc[3]);
    acc[4] = fmaf(w, __uint_as_float(f.z << 16),         acc[4]);
    acc[5] = fmaf(w, __uint_as_float(f.z & 0xffff0000u), acc[5]);
    acc[6] = fmaf(w, __uint_as_float(f.w << 16),         acc[6]);
    acc[7] = fmaf(w, __uint_as_float(f.w & 0xffff0000u), acc[7]);
}
__device__ __forceinline__ void mul8(float w, uint4 f, float acc[8]) {
    acc[0] = w * __uint_as_float(f.x << 16);
    acc[1] = w * __uint_as_float(f.x & 0xffff0000u);
    acc[2] = w * __uint_as_float(f.y << 16);
    acc[3] = w * __uint_as_float(f.y & 0xffff0000u);
    acc[4] = w * __uint_as_float(f.z << 16);
    acc[5] = w * __uint_as_float(f.z & 0xffff0000u);
    acc[6] = w * __uint_as_float(f.w << 16);
    acc[7] = w * __uint_as_float(f.w & 0xffff0000u);
}

// ---------------------------------------------------------------------------
// prep_a: pure streaming. x->bf16 convert; edge compaction to ushort2; cnt
// zeroing folded in.
__global__ void prep_a_kernel(const float* __restrict__ x, unsigned short* __restrict__ xb,
                              const void* __restrict__ raw, ushort2* __restrict__ ep0,
                              int* __restrict__ cnt) {
    int is64 = detect64((const int*)raw);
    int i = blockIdx.x * 256 + threadIdx.x;
    if (i < N_NODES * IN_DIM) xb[i] = f2bf(x[i]);
    if (i < N_NODES * CPAD) cnt[i] = 0;
    if (i < N_EDGES) {
        int s, d;
        if (is64) {
            s = (int)((const long long*)raw)[i];
            d = (int)((const long long*)raw)[N_EDGES + i];
        } else {
            s = ((const int*)raw)[i];
            d = ((const int*)raw)[N_EDGES + i];
        }
        ep0[i] = make_ushort2((unsigned short)s, (unsigned short)d);
    }
}

// ---------------------------------------------------------------------------
// hist: XCD-partitioned degree count + per-edge rank capture (atomic return
// value IS the within-node arrival rank).
__global__ __launch_bounds__(256) void hist_kernel(const ushort2* __restrict__ ep0,
                                                   int* __restrict__ cnt,
                                                   unsigned short* __restrict__ rank) {
    int xcd = blockIdx.x % N_XCD;
    int sl  = blockIdx.x / N_XCD;
    int lo  = xcd * NPX, hi = lo + NPX;
    int base = sl * SLICE;
#pragma unroll
    for (int j = 0; j < SLICE / 256; j++) {
        int e = base + j * 256 + threadIdx.x;
        if (e < N_EDGES) {
            int d = ep0[e].y;
            if (d >= lo && d < hi)
                rank[e] = (unsigned short)atomicAdd(&cnt[(size_t)d * CPAD], 1);
        }
    }
}

// ---------------------------------------------------------------------------
// scan1: block-local exclusive scan of cnt (padded) -> rowptr, bsum, dinv.
__global__ void scan1_kernel(const int* __restrict__ cnt, int* __restrict__ rowptr,
                             int* __restrict__ bsum, float* __restrict__ dinv) {
    __shared__ int s[SCAN_B];
    int t = threadIdx.x;
    int g = blockIdx.x * SCAN_B + t;
    int v = (g < N_NODES) ? cnt[(size_t)g * CPAD] : 0;
    if (g < N_NODES) dinv[g] = rsqrtf((float)(v + 1));   // +1 self loop
    s[t] = v;
    __syncthreads();
    for (int o = 1; o < SCAN_B; o <<= 1) {
        int add = (t >= o) ? s[t - o] : 0;
        __syncthreads();
        s[t] += add;
        __syncthreads();
    }
    if (g < N_NODES) rowptr[g] = s[t] - v;
    if (t == SCAN_B - 1) bsum[blockIdx.x] = s[t];
}

// scan23: each block redundantly scans the 196 bsums in LDS, applies offset.
__global__ void scan23_kernel(int* __restrict__ rowptr, const int* __restrict__ bsum) {
    __shared__ int s[256];
    int t = threadIdx.x;
    int v = (t < NB_SCAN) ? bsum[t] : 0;
    s[t] = v;
    __syncthreads();
    for (int o = 1; o < 256; o <<= 1) {
        int add = (t >= o) ? s[t - o] : 0;
        __syncthreads();
        s[t] += add;
        __syncthreads();
    }
    int excl = s[blockIdx.x] - bsum[blockIdx.x];
    int g = blockIdx.x * SCAN_B + t;
    if (g < N_NODES) rowptr[g] += excl;
    if (g == 0) rowptr[N_NODES] = N_EDGES;
}

// ---------------------------------------------------------------------------
// Deterministic scatter: single pass, no atomics. Slot = rowptr[dst] + rank.
__global__ __launch_bounds__(256) void scatter_kernel(
        const ushort2* __restrict__ ep0, const unsigned short* __restrict__ rank,
        const int* __restrict__ rowptr, const float* __restrict__ dinv,
        int2* __restrict__ ep) {
    int base = blockIdx.x * SLICE;
#pragma unroll
    for (int j = 0; j < SLICE / 256; j++) {
        int e = base + j * 256 + threadIdx.x;
        if (e < N_EDGES) {
            ushort2 sd = ep0[e];
            int p = rowptr[sd.y] + (int)rank[e];
            int s = sd.x;
            ep[p] = make_int2(s, __float_as_int(dinv[s]));
        }
    }
}

// ---------------------------------------------------------------------------
// Fused layer 1 (32-wide input): each 4-lane group owns ONE node; lane li
// owns features [8li,8li+8). No cross-lane reduction. 16 independent gather
// chains per wave (vs 1 before) -> latency hidden by MLP, not just TLP.
__global__ __launch_bounds__(256) void fused_layer32_kernel(
        const int* __restrict__ rowptr, const int2* __restrict__ ep,
        const float* __restrict__ dinv, const unsigned short* __restrict__ xb,
        const float* __restrict__ W1, const float* __restrict__ b1,
        unsigned short* __restrict__ out) {
    __shared__ __align__(16) float wlds[IN_DIM * 64];       // 8 KB
    __shared__ __align__(16) float sq[4][NPW32][IN_DIM];    // 8 KB
    for (int i = threadIdx.x; i < IN_DIM * 64; i += 256) wlds[i] = W1[i];
    __syncthreads();
    int lane = threadIdx.x & 63;
    int wav  = threadIdx.x >> 6;
    int grp  = lane >> 2;                                   // 0..15
    int li   = lane & 3;                                    // feature slice
    int gb   = lane & 60;                                   // group base lane
    const uint4* x4 = (const uint4*)xb;
    float bb = b1[lane];
    int vbase = ((int)blockIdx.x * 4 + wav) * NPW32;
    int v = vbase + grp;
    bool ok = v < N_NODES;
    int e0 = 0, e1 = 0;
    float dv = 0.0f;
    uint4 hv = make_uint4(0, 0, 0, 0);
    if (ok) {
        e0 = rowptr[v]; e1 = rowptr[v + 1];
        dv = dinv[v];
        hv = x4[(size_t)v * 4 + li];
    }
    int deg = e1 - e0;
    float acc[8];
    mul8(dv, hv, acc);                                      // self term
    int mx = deg;
    mx = max(mx, __shfl_xor(mx, 4));
    mx = max(mx, __shfl_xor(mx, 8));
    mx = max(mx, __shfl_xor(mx, 16));
    mx = max(mx, __shfl_xor(mx, 32));
    mx = __builtin_amdgcn_readfirstlane(mx);
    int2 pr = make_int2(0, 0);
    if (li < deg) pr = ep[e0 + li];
    for (int j0 = 0; j0 < mx; j0 += 4) {
        int2 prn = make_int2(0, 0);
        int idxn = j0 + 4 + li;
        if (idxn < deg) prn = ep[e0 + idxn];                // prefetch next round
#pragma unroll
        for (int jj = 0; jj < 4; jj++) {
            int ss = __shfl(pr.x, gb + jj);
            int ww = __shfl(pr.y, gb + jj);
            bool act = (j0 + jj) < deg;
            ss = act ? ss : 0;
            float w = act ? __int_as_float(ww) : 0.0f;
            uint4 f = x4[(size_t)ss * 4 + li];
            fma8(w, f, acc);
        }
        pr = prn;
    }
    {   // stage q (wave-local, no barrier)
        float4* qd = (float4*)&sq[wav][grp][li * 8];
        qd[0] = make_float4(dv * acc[0], dv * acc[1], dv * acc[2], dv * acc[3]);
        qd[1] = make_float4(dv * acc[4], dv * acc[5], dv * acc[6], dv * acc[7]);
    }
    float o[NPW32];
#pragma unroll
    for (int n = 0; n < NPW32; n++) o[n] = bb;
#pragma unroll
    for (int k4 = 0; k4 < IN_DIM / 4; k4++) {
        float w0 = wlds[(k4 * 4 + 0) * 64 + lane];
        float w1 = wlds[(k4 * 4 + 1) * 64 + lane];
        float w2 = wlds[(k4 * 4 + 2) * 64 + lane];
        float w3 = wlds[(k4 * 4 + 3) * 64 + lane];
#pragma unroll
        for (int n = 0; n < NPW32; n++) {
            float4 q = *(const float4*)&sq[wav][n][k4 * 4];
            o[n] = fmaf(q.x, w0, o[n]);
            o[n] = fmaf(q.y, w1, o[n]);
            o[n] = fmaf(q.z, w2, o[n]);
            o[n] = fmaf(q.w, w3, o[n]);
        }
    }
#pragma unroll
    for (int n = 0; n < NPW32; n++) {
        int vv = vbase + n;
        if (vv < N_NODES) out[(size_t)vv * 64 + lane] = f2bf(fmaxf(o[n], 0.0f));
    }
}

// Fused layer 2 (64-wide): 8-lane groups, one node each.
__global__ __launch_bounds__(256) void fused_layer64_kernel(
        const int* __restrict__ rowptr, const int2* __restrict__ ep,
        const float* __restrict__ dinv, const unsigned short* __restrict__ g,
        const float* __restrict__ W, const float* __restrict__ bias,
        unsigned short* __restrict__ out) {
    __shared__ __align__(16) float wlds[HIDDEN * 64];       // 16 KB
    __shared__ __align__(16) float sq[4][NPW64][HIDDEN];    // 8 KB
    for (int i = threadIdx.x; i < HIDDEN * 64; i += 256) wlds[i] = W[i];
    __syncthreads();
    int lane = threadIdx.x & 63;
    int wav  = threadIdx.x >> 6;
    int grp  = lane >> 3;                                   // 0..7
    int li   = lane & 7;
    int gb   = lane & 56;
    const uint4* g4 = (const uint4*)g;
    float bb = bias[lane];
    int vbase = ((int)blockIdx.x * 4 + wav) * NPW64;
    int v = vbase + grp;
    bool ok = v < N_NODES;
    int e0 = 0, e1 = 0;
    float dv = 0.0f;
    uint4 hv = make_uint4(0, 0, 0, 0);
    if (ok) {
        e0 = rowptr[v]; e1 = rowptr[v + 1];
        dv = dinv[v];
        hv = g4[(size_t)v * 8 + li];
    }
    int deg = e1 - e0;
    float acc[8];
    mul8(dv, hv, acc);
    int mx = deg;
    mx = max(mx, __shfl_xor(mx, 8));
    mx = max(mx, __shfl_xor(mx, 16));
    mx = max(mx, __shfl_xor(mx, 32));
    mx = __builtin_amdgcn_readfirstlane(mx);
    int2 pr = make_int2(0, 0);
    if (li < deg) pr = ep[e0 + li];
    for (int j0 = 0; j0 < mx; j0 += 8) {
        int2 prn = make_int2(0, 0);
        int idxn = j0 + 8 + li;
        if (idxn < deg) prn = ep[e0 + idxn];
#pragma unroll
        for (int jj = 0; jj < 8; jj++) {
            int ss = __shfl(pr.x, gb + jj);
            int ww = __shfl(pr.y, gb + jj);
            bool act = (j0 + jj) < deg;
            ss = act ? ss : 0;
            float w = act ? __int_as_float(ww) : 0.0f;
            uint4 f = g4[(size_t)ss * 8 + li];
            fma8(w, f, acc);
        }
        pr = prn;
    }
    {
        float4* qd = (float4*)&sq[wav][grp][li * 8];
        qd[0] = make_float4(dv * acc[0], dv * acc[1], dv * acc[2], dv * acc[3]);
        qd[1] = make_float4(dv * acc[4], dv * acc[5], dv * acc[6], dv * acc[7]);
    }
    float o[NPW64];
#pragma unroll
    for (int n = 0; n < NPW64; n++) o[n] = bb;
#pragma unroll
    for (int k4 = 0; k4 < HIDDEN / 4; k4++) {
        float w0 = wlds[(k4 * 4 + 0) * 64 + lane];
        float w1 = wlds[(k4 * 4 + 1) * 64 + lane];
        float w2 = wlds[(k4 * 4 + 2) * 64 + lane];
        float w3 = wlds[(k4 * 4 + 3) * 64 + lane];
#pragma unroll
        for (int n = 0; n < NPW64; n++) {
            float4 q = *(const float4*)&sq[wav][n][k4 * 4];
            o[n] = fmaf(q.x, w0, o[n]);
            o[n] = fmaf(q.y, w1, o[n]);
            o[n] = fmaf(q.z, w2, o[n]);
            o[n] = fmaf(q.w, w3, o[n]);
        }
    }
#pragma unroll
    for (int n = 0; n < NPW64; n++) {
        int vv = vbase + n;
        if (vv < N_NODES) out[(size_t)vv * 64 + lane] = f2bf(fmaxf(o[n], 0.0f));
    }
}

// Fused heads: same gather; apply with [Wmu|Wlv]; z = mu + exp(.5 lv) * eps.
__global__ __launch_bounds__(256) void fused_head_kernel(
        const int* __restrict__ rowptr, const int2* __restrict__ ep,
        const float* __restrict__ dinv, const unsigned short* __restrict__ g,
        const float* __restrict__ Wmu, const float* __restrict__ Wlv,
        const float* __restrict__ bmu, const float* __restrict__ blv,
        const float* __restrict__ eps, float* __restrict__ outz) {
    __shared__ __align__(16) float wlds[HIDDEN * 64];
    __shared__ __align__(16) float sq[4][NPW64][HIDDEN];
    for (int i = threadIdx.x; i < HIDDEN * 64; i += 256) {
        int k = i >> 6, col = i & 63;
        wlds[i] = (col < 32) ? Wmu[k * 32 + col] : Wlv[k * 32 + (col - 32)];
    }
    __syncthreads();
    int lane = threadIdx.x & 63;
    int wav  = threadIdx.x >> 6;
    int grp  = lane >> 3;
    int li   = lane & 7;
    int gb   = lane & 56;
    int f    = lane & 31;
    bool hi  = lane >= 32;
    const uint4* g4 = (const uint4*)g;
    float bb = hi ? blv[f] : bmu[f];
    float* z  = outz;
    float* mu = outz + (size_t)N_NODES * Z_DIM;
    float* lv = outz + 2 * (size_t)N_NODES * Z_DIM;
    int vbase = ((int)blockIdx.x * 4 + wav) * NPW64;
    int v = vbase + grp;
    bool ok = v < N_NODES;
    int e0 = 0, e1 = 0;
    float dv = 0.0f;
    uint4 hv = make_uint4(0, 0, 0, 0);
    if (ok) {
        e0 = rowptr[v]; e1 = rowptr[v + 1];
        dv = dinv[v];
        hv = g4[(size_t)v * 8 + li];
    }
    int deg = e1 - e0;
    float acc[8];
    mul8(dv, hv, acc);
    int mx = deg;
    mx = max(mx, __shfl_xor(mx, 8));
    mx = max(mx, __shfl_xor(mx, 16));
    mx = max(mx, __shfl_xor(mx, 32));
    mx = __builtin_amdgcn_readfirstlane(mx);
    int2 pr = make_int2(0, 0);
    if (li < deg) pr = ep[e0 + li];
    for (int j0 = 0; j0 < mx; j0 += 8) {
        int2 prn = make_int2(0, 0);
        int idxn = j0 + 8 + li;
        if (idxn < deg) prn = ep[e0 + idxn];
#pragma unroll
        for (int jj = 0; jj < 8; jj++) {
            int ss = __shfl(pr.x, gb + jj);
            int ww = __shfl(pr.y, gb + jj);
            bool act = (j0 + jj) < deg;
            ss = act ? ss : 0;
            float w = act ? __int_as_float(ww) : 0.0f;
            uint4 fr = g4[(size_t)ss * 8 + li];
            fma8(w, fr, acc);
        }
        pr = prn;
    }
    {
        float4* qd = (float4*)&sq[wav][grp][li * 8];
        qd[0] = make_float4(dv * acc[0], dv * acc[1], dv * acc[2], dv * acc[3]);
        qd[1] = make_float4(dv * acc[4], dv * acc[5], dv * acc[6], dv * acc[7]);
    }
    float o[NPW64];
#pragma unroll
    for (int n = 0; n < NPW64; n++) o[n] = bb;
#pragma unroll
    for (int k4 = 0; k4 < HIDDEN / 4; k4++) {
        float w0 = wlds[(k4 * 4 + 0) * 64 + lane];
        float w1 = wlds[(k4 * 4 + 1) * 64 + lane];
        float w2 = wlds[(k4 * 4 + 2) * 64 + lane];
        float w3 = wlds[(k4 * 4 + 3) * 64 + lane];
#pragma unroll
        for (int n = 0; n < NPW64; n++) {
            float4 q = *(const float4*)&sq[wav][n][k4 * 4];
            o[n] = fmaf(q.x, w0, o[n]);
            o[n] = fmaf(q.y, w1, o[n]);
            o[n] = fmaf(q.z, w2, o[n]);
            o[n] = fmaf(q.w, w3, o[n]);
        }
    }
#pragma unroll
    for (int n = 0; n < NPW64; n++) {
        int vv = vbase + n;
        if (vv < N_NODES) {
            float m  = o[n];
            float ev = eps[(size_t)vv * Z_DIM + f];
            float t  = expf(0.5f * m) * ev;
            float tlo = __shfl(t, lane | 32);
            size_t oo = (size_t)vv * Z_DIM + f;
            if (!hi) { mu[oo] = m; z[oo] = m + tlo; }
            else     { lv[oo] = m; }
        }
    }
}

// ---------------------------------------------------------------------------
extern "C" void kernel_launch(void* const* d_in, const int* in_sizes, int n_in,
                              void* d_out, int out_size, void* d_ws, size_t ws_size,
                              hipStream_t stream) {
    const float* x   = (const float*)d_in[0];
    const void*  ei  = d_in[1];
    const float* W1  = (const float*)d_in[2];
    const float* b1  = (const float*)d_in[3];
    const float* W2  = (const float*)d_in[4];
    const float* b2  = (const float*)d_in[5];
    const float* Wmu = (const float*)d_in[6];
    const float* bmu = (const float*)d_in[7];
    const float* Wlv = (const float*)d_in[8];
    const float* blv = (const float*)d_in[9];
    const float* eps = (const float*)d_in[10];
    float* out = (float*)d_out;
    (void)in_sizes; (void)n_in; (void)out_size; (void)ws_size;

    char* ws = (char*)d_ws;
    size_t off = 0;
    auto alloc = [&](size_t bytes) -> void* {
        void* p = ws + off;
        off += (bytes + 255) & ~(size_t)255;
        return p;
    };
    int2*           ep     = (int2*)alloc(sizeof(int2) * N_EDGES);       // 6.4 MB
    ushort2*        ep0    = (ushort2*)alloc(sizeof(ushort2) * N_EDGES); // 3.2 MB
    unsigned short* rank   = (unsigned short*)alloc(sizeof(short) * N_EDGES);  // 1.6 MB
    int*            rowptr = (int*)alloc(sizeof(int) * (N_NODES + 1));
    int*            cnt    = (int*)alloc(sizeof(int) * (size_t)N_NODES * CPAD); // 3.2 MB
    float*          dinv   = (float*)alloc(sizeof(float) * N_NODES);
    int*            bsum   = (int*)alloc(sizeof(int) * 256);
    unsigned short* xb     = (unsigned short*)alloc(sizeof(short) * (size_t)N_NODES * IN_DIM);  // 3.2 MB
    unsigned short* G      = (unsigned short*)alloc(sizeof(short) * (size_t)N_NODES * HIDDEN);  // 6.4 MB
    unsigned short* H      = (unsigned short*)alloc(sizeof(short) * (size_t)N_NODES * HIDDEN);  // 6.4 MB

    prep_a_kernel<<<(N_NODES * IN_DIM + 255) / 256, 256, 0, stream>>>(x, xb, ei, ep0, cnt);
    hist_kernel<<<SCAT_B, 256, 0, stream>>>(ep0, cnt, rank);
    scan1_kernel<<<NB_SCAN, SCAN_B, 0, stream>>>(cnt, rowptr, bsum, dinv);
    scan23_kernel<<<NB_SCAN, SCAN_B, 0, stream>>>(rowptr, bsum);
    scatter_kernel<<<N_SLICE, 256, 0, stream>>>(ep0, rank, rowptr, dinv, ep);
    // Layer 1: h1 = relu((A_norm x) W1 + b1)
    fused_layer32_kernel<<<FB32, 256, 0, stream>>>(rowptr, ep, dinv, xb, W1, b1, H);
    // Layer 2: h2 = relu((A_norm h1) W2 + b2)
    fused_layer64_kernel<<<FB64, 256, 0, stream>>>(rowptr, ep, dinv, H, W2, b2, G);
    // Heads: q = A_norm h2 ; mu|lv = q@[Wmu|Wlv]+b ; z = mu + exp(.5 lv) eps
    fused_head_kernel<<<FB64, 256, 0, stream>>>(rowptr, ep, dinv, G, Wmu, Wlv, bmu, blv, eps, out);
}

// Round 9
// 242.036 us; speedup vs baseline: 2.7350x; 1.4892x over previous
//
#include <hip/hip_runtime.h>
#include <math.h>

#define N_NODES 50000
#define N_EDGES 800000
#define IN_DIM 32
#define HIDDEN 64
#define Z_DIM 32
#define SCAN_B 256
#define NB_SCAN ((N_NODES + SCAN_B - 1) / SCAN_B)   // 196
#define N_XCD 8
#define NPX ((N_NODES + N_XCD - 1) / N_XCD)         // 6250 nodes per XCD range
#define SLICE 2048
#define N_SLICE ((N_EDGES + SLICE - 1) / SLICE)     // 391
#define SCAT_B (N_SLICE * N_XCD)                    // 3128 hist blocks
#define FB 2048                                     // 8192 waves for node kernels
#define CPAD 16                                     // cnt stride: 1 line/node

// bf16 (stored as ushort) <-> f32 helpers, RNE
__device__ __forceinline__ unsigned short f2bf(float f) {
    unsigned int u = __float_as_uint(f);
    u += 0x7fffu + ((u >> 16) & 1u);
    return (unsigned short)(u >> 16);
}

// wave-local edge dtype detect: int64 LE values < 2^31 have all-zero odd words.
__device__ __forceinline__ int detect64(const int* raw) {
    int lane = threadIdx.x & 63;
    int odd = raw[2 * lane + 1];
    unsigned long long b = __ballot(odd != 0);
    return (b == 0ULL) ? 1 : 0;
}

// ---------------------------------------------------------------------------
// prep_a: pure streaming. x->bf16; edge compaction to ushort2; cnt zeroing.
__global__ void prep_a_kernel(const float* __restrict__ x, unsigned short* __restrict__ xb,
                              const void* __restrict__ raw, ushort2* __restrict__ ep0,
                              int* __restrict__ cnt) {
    int is64 = detect64((const int*)raw);
    int i = blockIdx.x * 256 + threadIdx.x;
    if (i < N_NODES * IN_DIM) xb[i] = f2bf(x[i]);
    if (i < N_NODES * CPAD) cnt[i] = 0;
    if (i < N_EDGES) {
        int s, d;
        if (is64) {
            s = (int)((const long long*)raw)[i];
            d = (int)((const long long*)raw)[N_EDGES + i];
        } else {
            s = ((const int*)raw)[i];
            d = ((const int*)raw)[N_EDGES + i];
        }
        ep0[i] = make_ushort2((unsigned short)s, (unsigned short)d);
    }
}

// ---------------------------------------------------------------------------
// hist: XCD-partitioned degree count + per-edge rank capture (the atomic's
// return value IS the edge's within-node arrival rank).
__global__ __launch_bounds__(256) void hist_kernel(const ushort2* __restrict__ ep0,
                                                   int* __restrict__ cnt,
                                                   unsigned short* __restrict__ rank) {
    int xcd = blockIdx.x % N_XCD;
    int sl  = blockIdx.x / N_XCD;
    int lo  = xcd * NPX, hi = lo + NPX;
    int base = sl * SLICE;
#pragma unroll
    for (int j = 0; j < SLICE / 256; j++) {
        int e = base + j * 256 + threadIdx.x;
        if (e < N_EDGES) {
            int d = ep0[e].y;
            if (d >= lo && d < hi)
                rank[e] = (unsigned short)atomicAdd(&cnt[(size_t)d * CPAD], 1);
        }
    }
}

// ---------------------------------------------------------------------------
// scan1: block-local exclusive scan of cnt (padded) -> rowptr, bsum, dinv.
__global__ void scan1_kernel(const int* __restrict__ cnt, int* __restrict__ rowptr,
                             int* __restrict__ bsum, float* __restrict__ dinv) {
    __shared__ int s[SCAN_B];
    int t = threadIdx.x;
    int g = blockIdx.x * SCAN_B + t;
    int v = (g < N_NODES) ? cnt[(size_t)g * CPAD] : 0;
    if (g < N_NODES) dinv[g] = rsqrtf((float)(v + 1));   // +1 self loop
    s[t] = v;
    __syncthreads();
    for (int o = 1; o < SCAN_B; o <<= 1) {
        int add = (t >= o) ? s[t - o] : 0;
        __syncthreads();
        s[t] += add;
        __syncthreads();
    }
    if (g < N_NODES) rowptr[g] = s[t] - v;
    if (t == SCAN_B - 1) bsum[blockIdx.x] = s[t];
}

// scan23: each block redundantly scans the 196 bsums in LDS, applies offset.
__global__ void scan23_kernel(int* __restrict__ rowptr, const int* __restrict__ bsum) {
    __shared__ int s[256];
    int t = threadIdx.x;
    int v = (t < NB_SCAN) ? bsum[t] : 0;
    s[t] = v;
    __syncthreads();
    for (int o = 1; o < 256; o <<= 1) {
        int add = (t >= o) ? s[t - o] : 0;
        __syncthreads();
        s[t] += add;
        __syncthreads();
    }
    int excl = s[blockIdx.x] - bsum[blockIdx.x];
    int g = blockIdx.x * SCAN_B + t;
    if (g < N_NODES) rowptr[g] += excl;
    if (g == 0) rowptr[N_NODES] = N_EDGES;
}

// ---------------------------------------------------------------------------
// Deterministic scatter: single pass, no atomics. Slot = rowptr[dst] + rank.
__global__ __launch_bounds__(256) void scatter_kernel(
        const ushort2* __restrict__ ep0, const unsigned short* __restrict__ rank,
        const int* __restrict__ rowptr, const float* __restrict__ dinv,
        int2* __restrict__ ep) {
    int base = blockIdx.x * SLICE;
#pragma unroll
    for (int j = 0; j < SLICE / 256; j++) {
        int e = base + j * 256 + threadIdx.x;
        if (e < N_EDGES) {
            ushort2 sd = ep0[e];
            int p = rowptr[sd.y] + (int)rank[e];
            int s = sd.x;
            ep[p] = make_int2(s, __float_as_int(dinv[s]));
        }
    }
}

// ---------------------------------------------------------------------------
// Dual-node 64-wide aggregation: the wave runs TWO nodes' batch loops
// interleaved -> 8 gathers in flight instead of 4 (latency-bound fix without
// register blowup). uint2 gathers: 16 lanes x 8B = 128B row, 4 edges/load.
// Per-lane edge index via ds_bpermute; exhausted/invalid node contributes w=0.
__device__ __forceinline__ void agg_dual64(
        int e0A, int e1A, int2 prA, int e0B, int e1B, int2 prB,
        const int2* __restrict__ ep, const uint2* __restrict__ g2,
        int lane, int gsel, int c, float accA[4], float accB[4]) {
    int bA = e0A, bB = e0B;
    while (bA < e1A || bB < e1B) {
        int cA = e1A - bA; cA = cA < 0 ? 0 : (cA > 64 ? 64 : cA);
        int cB = e1B - bB; cB = cB < 0 ? 0 : (cB > 64 ? 64 : cB);
        int mj = cA > cB ? cA : cB;
        for (int j = 0; j < mj; j += 16) {
            uint2 fA[4], fB[4]; float wA[4], wB[4];
#pragma unroll
            for (int u = 0; u < 4; u++) {
                int idx = j + u * 4 + gsel;
                int clA = idx < cA ? idx : (cA > 0 ? cA - 1 : 0);
                int clB = idx < cB ? idx : (cB > 0 ? cB - 1 : 0);
                int sA  = __builtin_amdgcn_ds_bpermute(clA << 2, prA.x);
                int wwA = __builtin_amdgcn_ds_bpermute(clA << 2, prA.y);
                int sB  = __builtin_amdgcn_ds_bpermute(clB << 2, prB.x);
                int wwB = __builtin_amdgcn_ds_bpermute(clB << 2, prB.y);
                wA[u] = idx < cA ? __int_as_float(wwA) : 0.0f;
                wB[u] = idx < cB ? __int_as_float(wwB) : 0.0f;
                fA[u] = g2[(size_t)sA * 16 + c];
                fB[u] = g2[(size_t)sB * 16 + c];
            }
#pragma unroll
            for (int u = 0; u < 4; u++) {
                accA[0] = fmaf(wA[u], __uint_as_float(fA[u].x << 16),         accA[0]);
                accA[1] = fmaf(wA[u], __uint_as_float(fA[u].x & 0xffff0000u), accA[1]);
                accA[2] = fmaf(wA[u], __uint_as_float(fA[u].y << 16),         accA[2]);
                accA[3] = fmaf(wA[u], __uint_as_float(fA[u].y & 0xffff0000u), accA[3]);
                accB[0] = fmaf(wB[u], __uint_as_float(fB[u].x << 16),         accB[0]);
                accB[1] = fmaf(wB[u], __uint_as_float(fB[u].x & 0xffff0000u), accB[1]);
                accB[2] = fmaf(wB[u], __uint_as_float(fB[u].y << 16),         accB[2]);
                accB[3] = fmaf(wB[u], __uint_as_float(fB[u].y & 0xffff0000u), accB[3]);
            }
        }
        bA += 64; bB += 64;
        if (bA < e1A) { int i2 = bA + lane; prA = ep[i2 < e1A ? i2 : e1A - 1]; }
        if (bB < e1B) { int i2 = bB + lane; prB = ep[i2 < e1B ? i2 : e1B - 1]; }
    }
}

// Dual-node 32-wide aggregation: 8 lanes x 8B = 64B row, 8 edges/load.
__device__ __forceinline__ void agg_dual32(
        int e0A, int e1A, int2 prA, int e0B, int e1B, int2 prB,
        const int2* __restrict__ ep, const uint2* __restrict__ x2,
        int lane, int gsel, int c, float accA[4], float accB[4]) {
    int bA = e0A, bB = e0B;
    while (bA < e1A || bB < e1B) {
        int cA = e1A - bA; cA = cA < 0 ? 0 : (cA > 64 ? 64 : cA);
        int cB = e1B - bB; cB = cB < 0 ? 0 : (cB > 64 ? 64 : cB);
        int mj = cA > cB ? cA : cB;
        for (int j = 0; j < mj; j += 16) {
            uint2 fA[2], fB[2]; float wA[2], wB[2];
#pragma unroll
            for (int u = 0; u < 2; u++) {
                int idx = j + u * 8 + gsel;
                int clA = idx < cA ? idx : (cA > 0 ? cA - 1 : 0);
                int clB = idx < cB ? idx : (cB > 0 ? cB - 1 : 0);
                int sA  = __builtin_amdgcn_ds_bpermute(clA << 2, prA.x);
                int wwA = __builtin_amdgcn_ds_bpermute(clA << 2, prA.y);
                int sB  = __builtin_amdgcn_ds_bpermute(clB << 2, prB.x);
                int wwB = __builtin_amdgcn_ds_bpermute(clB << 2, prB.y);
                wA[u] = idx < cA ? __int_as_float(wwA) : 0.0f;
                wB[u] = idx < cB ? __int_as_float(wwB) : 0.0f;
                fA[u] = x2[(size_t)sA * 8 + c];
                fB[u] = x2[(size_t)sB * 8 + c];
            }
#pragma unroll
            for (int u = 0; u < 2; u++) {
                accA[0] = fmaf(wA[u], __uint_as_float(fA[u].x << 16),         accA[0]);
                accA[1] = fmaf(wA[u], __uint_as_float(fA[u].x & 0xffff0000u), accA[1]);
                accA[2] = fmaf(wA[u], __uint_as_float(fA[u].y << 16),         accA[2]);
                accA[3] = fmaf(wA[u], __uint_as_float(fA[u].y & 0xffff0000u), accA[3]);
                accB[0] = fmaf(wB[u], __uint_as_float(fB[u].x << 16),         accB[0]);
                accB[1] = fmaf(wB[u], __uint_as_float(fB[u].x & 0xffff0000u), accB[1]);
                accB[2] = fmaf(wB[u], __uint_as_float(fB[u].y << 16),         accB[2]);
                accB[3] = fmaf(wB[u], __uint_as_float(fB[u].y & 0xffff0000u), accB[3]);
            }
        }
        bA += 64; bB += 64;
        if (bA < e1A) { int i2 = bA + lane; prA = ep[i2 < e1A ? i2 : e1A - 1]; }
        if (bB < e1B) { int i2 = bB + lane; prB = ep[i2 < e1B ? i2 : e1B - 1]; }
    }
}

// Node-state loader (exec-masked first edge batch).
#define LOAD_STATE(v, e0, e1, dv, hv, pr, HLOAD)                            \
    {                                                                       \
        e0 = rowptr[v]; e1 = rowptr[v + 1];                                 \
        dv = dinv[v];                                                       \
        hv = HLOAD;                                                         \
        if (lane < e1 - e0) pr = ep[e0 + lane];                             \
    }

// ---------------------------------------------------------------------------
// Fused layer 1: q = normAgg(xb) [32-wide], out = relu(q @ W1 + b1).
// Two nodes (v, v+nw) per wave iteration; stride 2*nw.
__global__ __launch_bounds__(256) void fused_layer32_kernel(
        const int* __restrict__ rowptr, const int2* __restrict__ ep,
        const float* __restrict__ dinv, const unsigned short* __restrict__ xb,
        const float* __restrict__ W1, const float* __restrict__ b1,
        unsigned short* __restrict__ out) {
    __shared__ float sq[4][2][IN_DIM];
    int lane = threadIdx.x & 63;
    int wav  = threadIdx.x >> 6;
    int gsel = lane >> 3;                                    // 0..7
    int c    = lane & 7;                                     // 8 x uint2 = 64B row
    const uint2* x2 = (const uint2*)xb;
    float wcol[IN_DIM];
#pragma unroll
    for (int k = 0; k < IN_DIM; k++) wcol[k] = W1[k * 64 + lane];
    float bb = b1[lane];
    int wid = __builtin_amdgcn_readfirstlane((int)((blockIdx.x * blockDim.x + threadIdx.x) >> 6));
    int nw  = (gridDim.x * blockDim.x) >> 6;
    int vA = wid;
    if (vA >= N_NODES) return;
    int e0A = 0, e1A = 0, e0B = 0, e1B = 0;
    float dvA = 0.0f, dvB = 0.0f;
    uint2 hvA = make_uint2(0, 0), hvB = make_uint2(0, 0);
    int2 prA = make_int2(0, 0), prB = make_int2(0, 0);
    LOAD_STATE(vA, e0A, e1A, dvA, hvA, prA, x2[(size_t)vA * 8 + c])
    {
        int vB = vA + nw;
        if (vB < N_NODES)
            LOAD_STATE(vB, e0B, e1B, dvB, hvB, prB, x2[(size_t)vB * 8 + c])
    }
    while (vA < N_NODES) {
        int vB = vA + nw;
        int vA2 = vA + 2 * nw;
        // prefetch next pair
        int e0A2 = 0, e1A2 = 0, e0B2 = 0, e1B2 = 0;
        float dvA2 = 0.0f, dvB2 = 0.0f;
        uint2 hvA2 = make_uint2(0, 0), hvB2 = make_uint2(0, 0);
        int2 prA2 = make_int2(0, 0), prB2 = make_int2(0, 0);
        if (vA2 < N_NODES)
            LOAD_STATE(vA2, e0A2, e1A2, dvA2, hvA2, prA2, x2[(size_t)vA2 * 8 + c])
        if (vA2 + nw < N_NODES) {
            int vB2 = vA2 + nw;
            LOAD_STATE(vB2, e0B2, e1B2, dvB2, hvB2, prB2, x2[(size_t)vB2 * 8 + c])
        }
        float svA = (gsel == 0) ? dvA : 0.0f;
        float svB = (gsel == 0) ? dvB : 0.0f;
        float accA[4], accB[4];
        accA[0] = svA * __uint_as_float(hvA.x << 16);
        accA[1] = svA * __uint_as_float(hvA.x & 0xffff0000u);
        accA[2] = svA * __uint_as_float(hvA.y << 16);
        accA[3] = svA * __uint_as_float(hvA.y & 0xffff0000u);
        accB[0] = svB * __uint_as_float(hvB.x << 16);
        accB[1] = svB * __uint_as_float(hvB.x & 0xffff0000u);
        accB[2] = svB * __uint_as_float(hvB.y << 16);
        accB[3] = svB * __uint_as_float(hvB.y & 0xffff0000u);
        agg_dual32(e0A, e1A, prA, e0B, e1B, prB, ep, x2, lane, gsel, c, accA, accB);
#pragma unroll
        for (int i = 0; i < 4; i++) {
            accA[i] += __shfl_xor(accA[i], 8);
            accA[i] += __shfl_xor(accA[i], 16);
            accA[i] += __shfl_xor(accA[i], 32);
            accB[i] += __shfl_xor(accB[i], 8);
            accB[i] += __shfl_xor(accB[i], 16);
            accB[i] += __shfl_xor(accB[i], 32);
        }
        if (lane < 8) {
            ((float4*)(&sq[wav][0][0]))[c] =
                make_float4(dvA * accA[0], dvA * accA[1], dvA * accA[2], dvA * accA[3]);
            ((float4*)(&sq[wav][1][0]))[c] =
                make_float4(dvB * accB[0], dvB * accB[1], dvB * accB[2], dvB * accB[3]);
        }
        float oA = bb, oB = bb;
        const float4* qA = (const float4*)(&sq[wav][0][0]);
        const float4* qB = (const float4*)(&sq[wav][1][0]);
#pragma unroll
        for (int k = 0; k < IN_DIM / 4; k++) {
            float4 ta = qA[k], tb = qB[k];
            oA = fmaf(ta.x, wcol[4 * k + 0], oA);
            oA = fmaf(ta.y, wcol[4 * k + 1], oA);
            oA = fmaf(ta.z, wcol[4 * k + 2], oA);
            oA = fmaf(ta.w, wcol[4 * k + 3], oA);
            oB = fmaf(tb.x, wcol[4 * k + 0], oB);
            oB = fmaf(tb.y, wcol[4 * k + 1], oB);
            oB = fmaf(tb.z, wcol[4 * k + 2], oB);
            oB = fmaf(tb.w, wcol[4 * k + 3], oB);
        }
        out[(size_t)vA * 64 + lane] = f2bf(fmaxf(oA, 0.0f));
        if (vB < N_NODES) out[(size_t)vB * 64 + lane] = f2bf(fmaxf(oB, 0.0f));
        vA = vA2;
        e0A = e0A2; e1A = e1A2; dvA = dvA2; hvA = hvA2; prA = prA2;
        e0B = e0B2; e1B = e1B2; dvB = dvB2; hvB = hvB2; prB = prB2;
    }
}

// Fused layer 2: q = normAgg(g) [64-wide], out = relu(q @ W + b). Dual-node.
__global__ __launch_bounds__(256) void fused_layer64_kernel(
        const int* __restrict__ rowptr, const int2* __restrict__ ep,
        const float* __restrict__ dinv, const unsigned short* __restrict__ g,
        const float* __restrict__ W, const float* __restrict__ bias,
        unsigned short* __restrict__ out) {
    __shared__ float sq[4][2][HIDDEN];
    int lane = threadIdx.x & 63;
    int wav  = threadIdx.x >> 6;
    int gsel = lane >> 4;                                    // 0..3
    int c    = lane & 15;                                    // 16 x uint2 = 128B row
    const uint2* g2 = (const uint2*)g;
    float wcol[HIDDEN];
#pragma unroll
    for (int k = 0; k < HIDDEN; k++) wcol[k] = W[k * 64 + lane];
    float bb = bias[lane];
    int wid = __builtin_amdgcn_readfirstlane((int)((blockIdx.x * blockDim.x + threadIdx.x) >> 6));
    int nw  = (gridDim.x * blockDim.x) >> 6;
    int vA = wid;
    if (vA >= N_NODES) return;
    int e0A = 0, e1A = 0, e0B = 0, e1B = 0;
    float dvA = 0.0f, dvB = 0.0f;
    uint2 hvA = make_uint2(0, 0), hvB = make_uint2(0, 0);
    int2 prA = make_int2(0, 0), prB = make_int2(0, 0);
    LOAD_STATE(vA, e0A, e1A, dvA, hvA, prA, g2[(size_t)vA * 16 + c])
    {
        int vB = vA + nw;
        if (vB < N_NODES)
            LOAD_STATE(vB, e0B, e1B, dvB, hvB, prB, g2[(size_t)vB * 16 + c])
    }
    while (vA < N_NODES) {
        int vB = vA + nw;
        int vA2 = vA + 2 * nw;
        int e0A2 = 0, e1A2 = 0, e0B2 = 0, e1B2 = 0;
        float dvA2 = 0.0f, dvB2 = 0.0f;
        uint2 hvA2 = make_uint2(0, 0), hvB2 = make_uint2(0, 0);
        int2 prA2 = make_int2(0, 0), prB2 = make_int2(0, 0);
        if (vA2 < N_NODES)
            LOAD_STATE(vA2, e0A2, e1A2, dvA2, hvA2, prA2, g2[(size_t)vA2 * 16 + c])
        if (vA2 + nw < N_NODES) {
            int vB2 = vA2 + nw;
            LOAD_STATE(vB2, e0B2, e1B2, dvB2, hvB2, prB2, g2[(size_t)vB2 * 16 + c])
        }
        float svA = (gsel == 0) ? dvA : 0.0f;
        float svB = (gsel == 0) ? dvB : 0.0f;
        float accA[4], accB[4];
        accA[0] = svA * __uint_as_float(hvA.x << 16);
        accA[1] = svA * __uint_as_float(hvA.x & 0xffff0000u);
        accA[2] = svA * __uint_as_float(hvA.y << 16);
        accA[3] = svA * __uint_as_float(hvA.y & 0xffff0000u);
        accB[0] = svB * __uint_as_float(hvB.x << 16);
        accB[1] = svB * __uint_as_float(hvB.x & 0xffff0000u);
        accB[2] = svB * __uint_as_float(hvB.y << 16);
        accB[3] = svB * __uint_as_float(hvB.y & 0xffff0000u);
        agg_dual64(e0A, e1A, prA, e0B, e1B, prB, ep, g2, lane, gsel, c, accA, accB);
#pragma unroll
        for (int i = 0; i < 4; i++) {
            accA[i] += __shfl_xor(accA[i], 16);
            accA[i] += __shfl_xor(accA[i], 32);
            accB[i] += __shfl_xor(accB[i], 16);
            accB[i] += __shfl_xor(accB[i], 32);
        }
        if (lane < 16) {
            ((float4*)(&sq[wav][0][0]))[c] =
                make_float4(dvA * accA[0], dvA * accA[1], dvA * accA[2], dvA * accA[3]);
            ((float4*)(&sq[wav][1][0]))[c] =
                make_float4(dvB * accB[0], dvB * accB[1], dvB * accB[2], dvB * accB[3]);
        }
        float oA = bb, oB = bb;
        const float4* qA = (const float4*)(&sq[wav][0][0]);
        const float4* qB = (const float4*)(&sq[wav][1][0]);
#pragma unroll
        for (int k = 0; k < HIDDEN / 4; k++) {
            float4 ta = qA[k], tb = qB[k];
            oA = fmaf(ta.x, wcol[4 * k + 0], oA);
            oA = fmaf(ta.y, wcol[4 * k + 1], oA);
            oA = fmaf(ta.z, wcol[4 * k + 2], oA);
            oA = fmaf(ta.w, wcol[4 * k + 3], oA);
            oB = fmaf(tb.x, wcol[4 * k + 0], oB);
            oB = fmaf(tb.y, wcol[4 * k + 1], oB);
            oB = fmaf(tb.z, wcol[4 * k + 2], oB);
            oB = fmaf(tb.w, wcol[4 * k + 3], oB);
        }
        out[(size_t)vA * 64 + lane] = f2bf(fmaxf(oA, 0.0f));
        if (vB < N_NODES) out[(size_t)vB * 64 + lane] = f2bf(fmaxf(oB, 0.0f));
        vA = vA2;
        e0A = e0A2; e1A = e1A2; dvA = dvA2; hvA = hvA2; prA = prA2;
        e0B = e0B2; e1B = e1B2; dvB = dvB2; hvB = hvB2; prB = prB2;
    }
}

// Fused heads: q = normAgg(h2); mu (lanes<32) / lv (lanes>=32); z = mu+exp(.5lv)eps.
__global__ __launch_bounds__(256) void fused_head_kernel(
        const int* __restrict__ rowptr, const int2* __restrict__ ep,
        const float* __restrict__ dinv, const unsigned short* __restrict__ g,
        const float* __restrict__ Wmu, const float* __restrict__ Wlv,
        const float* __restrict__ bmu, const float* __restrict__ blv,
        const float* __restrict__ eps, float* __restrict__ outz) {
    __shared__ float sq[4][2][HIDDEN];
    int lane = threadIdx.x & 63;
    int wav  = threadIdx.x >> 6;
    int gsel = lane >> 4;
    int c    = lane & 15;
    int f = lane & 31;
    bool hi = lane >= 32;
    const uint2* g2 = (const uint2*)g;
    float wcol[HIDDEN];
#pragma unroll
    for (int k = 0; k < HIDDEN; k++)
        wcol[k] = hi ? Wlv[k * 32 + f] : Wmu[k * 32 + f];
    float bb = hi ? blv[f] : bmu[f];
    float* z  = outz;
    float* mu = outz + (size_t)N_NODES * Z_DIM;
    float* lv = outz + 2 * (size_t)N_NODES * Z_DIM;
    int wid = __builtin_amdgcn_readfirstlane((int)((blockIdx.x * blockDim.x + threadIdx.x) >> 6));
    int nw  = (gridDim.x * blockDim.x) >> 6;
    int vA = wid;
    if (vA >= N_NODES) return;
    int e0A = 0, e1A = 0, e0B = 0, e1B = 0;
    float dvA = 0.0f, dvB = 0.0f;
    uint2 hvA = make_uint2(0, 0), hvB = make_uint2(0, 0);
    int2 prA = make_int2(0, 0), prB = make_int2(0, 0);
    LOAD_STATE(vA, e0A, e1A, dvA, hvA, prA, g2[(size_t)vA * 16 + c])
    {
        int vB = vA + nw;
        if (vB < N_NODES)
            LOAD_STATE(vB, e0B, e1B, dvB, hvB, prB, g2[(size_t)vB * 16 + c])
    }
    while (vA < N_NODES) {
        int vB = vA + nw;
        int vA2 = vA + 2 * nw;
        int e0A2 = 0, e1A2 = 0, e0B2 = 0, e1B2 = 0;
        float dvA2 = 0.0f, dvB2 = 0.0f;
        uint2 hvA2 = make_uint2(0, 0), hvB2 = make_uint2(0, 0);
        int2 prA2 = make_int2(0, 0), prB2 = make_int2(0, 0);
        if (vA2 < N_NODES)
            LOAD_STATE(vA2, e0A2, e1A2, dvA2, hvA2, prA2, g2[(size_t)vA2 * 16 + c])
        if (vA2 + nw < N_NODES) {
            int vB2 = vA2 + nw;
            LOAD_STATE(vB2, e0B2, e1B2, dvB2, hvB2, prB2, g2[(size_t)vB2 * 16 + c])
        }
        float svA = (gsel == 0) ? dvA : 0.0f;
        float svB = (gsel == 0) ? dvB : 0.0f;
        float accA[4], accB[4];
        accA[0] = svA * __uint_as_float(hvA.x << 16);
        accA[1] = svA * __uint_as_float(hvA.x & 0xffff0000u);
        accA[2] = svA * __uint_as_float(hvA.y << 16);
        accA[3] = svA * __uint_as_float(hvA.y & 0xffff0000u);
        accB[0] = svB * __uint_as_float(hvB.x << 16);
        accB[1] = svB * __uint_as_float(hvB.x & 0xffff0000u);
        accB[2] = svB * __uint_as_float(hvB.y << 16);
        accB[3] = svB * __uint_as_float(hvB.y & 0xffff0000u);
        agg_dual64(e0A, e1A, prA, e0B, e1B, prB, ep, g2, lane, gsel, c, accA, accB);
#pragma unroll
        for (int i = 0; i < 4; i++) {
            accA[i] += __shfl_xor(accA[i], 16);
            accA[i] += __shfl_xor(accA[i], 32);
            accB[i] += __shfl_xor(accB[i], 16);
            accB[i] += __shfl_xor(accB[i], 32);
        }
        if (lane < 16) {
            ((float4*)(&sq[wav][0][0]))[c] =
                make_float4(dvA * accA[0], dvA * accA[1], dvA * accA[2], dvA * accA[3]);
            ((float4*)(&sq[wav][1][0]))[c] =
                make_float4(dvB * accB[0], dvB * accB[1], dvB * accB[2], dvB * accB[3]);
        }
        float mA = bb, mB = bb;
        const float4* qA = (const float4*)(&sq[wav][0][0]);
        const float4* qB = (const float4*)(&sq[wav][1][0]);
#pragma unroll
        for (int k = 0; k < HIDDEN / 4; k++) {
            float4 ta = qA[k], tb = qB[k];
            mA = fmaf(ta.x, wcol[4 * k + 0], mA);
            mA = fmaf(ta.y, wcol[4 * k + 1], mA);
            mA = fmaf(ta.z, wcol[4 * k + 2], mA);
            mA = fmaf(ta.w, wcol[4 * k + 3], mA);
            mB = fmaf(tb.x, wcol[4 * k + 0], mB);
            mB = fmaf(tb.y, wcol[4 * k + 1], mB);
            mB = fmaf(tb.z, wcol[4 * k + 2], mB);
            mB = fmaf(tb.w, wcol[4 * k + 3], mB);
        }
        {
            float ev = eps[(size_t)vA * Z_DIM + f];
            float t  = expf(0.5f * mA) * ev;
            float tlo = __shfl(t, lane | 32);
            size_t o = (size_t)vA * Z_DIM + f;
            if (!hi) { mu[o] = mA; z[o] = mA + tlo; }
            else     { lv[o] = mA; }
        }
        if (vB < N_NODES) {
            float ev = eps[(size_t)vB * Z_DIM + f];
            float t  = expf(0.5f * mB) * ev;
            float tlo = __shfl(t, lane | 32);
            size_t o = (size_t)vB * Z_DIM + f;
            if (!hi) { mu[o] = mB; z[o] = mB + tlo; }
            else     { lv[o] = mB; }
        }
        vA = vA2;
        e0A = e0A2; e1A = e1A2; dvA = dvA2; hvA = hvA2; prA = prA2;
        e0B = e0B2; e1B = e1B2; dvB = dvB2; hvB = hvB2; prB = prB2;
    }
}

// ---------------------------------------------------------------------------
extern "C" void kernel_launch(void* const* d_in, const int* in_sizes, int n_in,
                              void* d_out, int out_size, void* d_ws, size_t ws_size,
                              hipStream_t stream) {
    const float* x   = (const float*)d_in[0];
    const void*  ei  = d_in[1];
    const float* W1  = (const float*)d_in[2];
    const float* b1  = (const float*)d_in[3];
    const float* W2  = (const float*)d_in[4];
    const float* b2  = (const float*)d_in[5];
    const float* Wmu = (const float*)d_in[6];
    const float* bmu = (const float*)d_in[7];
    const float* Wlv = (const float*)d_in[8];
    const float* blv = (const float*)d_in[9];
    const float* eps = (const float*)d_in[10];
    float* out = (float*)d_out;
    (void)in_sizes; (void)n_in; (void)out_size; (void)ws_size;

    char* ws = (char*)d_ws;
    size_t off = 0;
    auto alloc = [&](size_t bytes) -> void* {
        void* p = ws + off;
        off += (bytes + 255) & ~(size_t)255;
        return p;
    };
    int2*           ep     = (int2*)alloc(sizeof(int2) * N_EDGES);       // 6.4 MB
    ushort2*        ep0    = (ushort2*)alloc(sizeof(ushort2) * N_EDGES); // 3.2 MB
    unsigned short* rank   = (unsigned short*)alloc(sizeof(short) * N_EDGES);  // 1.6 MB
    int*            rowptr = (int*)alloc(sizeof(int) * (N_NODES + 1));
    int*            cnt    = (int*)alloc(sizeof(int) * (size_t)N_NODES * CPAD); // 3.2 MB
    float*          dinv   = (float*)alloc(sizeof(float) * N_NODES);
    int*            bsum   = (int*)alloc(sizeof(int) * 256);
    unsigned short* xb     = (unsigned short*)alloc(sizeof(short) * (size_t)N_NODES * IN_DIM);  // 3.2 MB
    unsigned short* G      = (unsigned short*)alloc(sizeof(short) * (size_t)N_NODES * HIDDEN);  // 6.4 MB
    unsigned short* H      = (unsigned short*)alloc(sizeof(short) * (size_t)N_NODES * HIDDEN);  // 6.4 MB

    prep_a_kernel<<<(N_NODES * IN_DIM + 255) / 256, 256, 0, stream>>>(x, xb, ei, ep0, cnt);
    hist_kernel<<<SCAT_B, 256, 0, stream>>>(ep0, cnt, rank);
    scan1_kernel<<<NB_SCAN, SCAN_B, 0, stream>>>(cnt, rowptr, bsum, dinv);
    scan23_kernel<<<NB_SCAN, SCAN_B, 0, stream>>>(rowptr, bsum);
    scatter_kernel<<<N_SLICE, 256, 0, stream>>>(ep0, rank, rowptr, dinv, ep);
    // Layer 1: h1 = relu((A_norm x) W1 + b1)
    fused_layer32_kernel<<<FB, 256, 0, stream>>>(rowptr, ep, dinv, xb, W1, b1, H);
    // Layer 2: h2 = relu((A_norm h1) W2 + b2)
    fused_layer64_kernel<<<FB, 256, 0, stream>>>(rowptr, ep, dinv, H, W2, b2, G);
    // Heads: q = A_norm h2 ; mu|lv = q@[Wmu|Wlv]+b ; z = mu + exp(.5 lv) eps
    fused_head_kernel<<<FB, 256, 0, stream>>>(rowptr, ep, dinv, G, Wmu, Wlv, bmu, blv, eps, out);
}

// Round 10
// 240.007 us; speedup vs baseline: 2.7581x; 1.0085x over previous
//
#include <hip/hip_runtime.h>
#include <math.h>

#define N_NODES 50000
#define N_EDGES 800000
#define IN_DIM 32
#define HIDDEN 64
#define Z_DIM 32
#define SCAN_B 256
#define NB_SCAN ((N_NODES + SCAN_B - 1) / SCAN_B)   // 196
#define N_XCD 8
#define NPX ((N_NODES + N_XCD - 1) / N_XCD)         // 6250 nodes per XCD range
#define SLICE 2048
#define N_SLICE ((N_EDGES + SLICE - 1) / SLICE)     // 391
#define SCAT_B (N_SLICE * N_XCD)                    // 3128 hist blocks
#define FB 2048                                     // 8192 waves for node kernels
#define CPAD 16                                     // cnt stride: 1 line/node
#define PREP_T 200000                               // max(1.6M/8, 800k/4) threads
#define PREP_B ((PREP_T + 255) / 256)               // 782 blocks

// bf16 (stored as ushort) <-> f32 helpers, RNE
__device__ __forceinline__ unsigned short f2bf(float f) {
    unsigned int u = __float_as_uint(f);
    u += 0x7fffu + ((u >> 16) & 1u);
    return (unsigned short)(u >> 16);
}

// wave-local edge dtype detect: int64 LE values < 2^31 have all-zero odd words.
__device__ __forceinline__ int detect64(const int* raw) {
    int lane = threadIdx.x & 63;
    int odd = raw[2 * lane + 1];
    unsigned long long b = __ballot(odd != 0);
    return (b == 0ULL) ? 1 : 0;
}

// pack two bf16 (from floats) into one uint
__device__ __forceinline__ unsigned int pack2bf(float a, float b) {
    return (unsigned int)f2bf(a) | ((unsigned int)f2bf(b) << 16);
}

// ---------------------------------------------------------------------------
// prep_a (VECTORIZED, 16B/lane): x->bf16 (8 elems/thread), cnt zero (4/thread),
// edge compaction to ushort2 (8 edges/thread). Was 0.65 TB/s with scalar
// accesses (46us); streaming rate needs wide loads/stores.
__global__ __launch_bounds__(256) void prep_a_kernel(
        const float* __restrict__ x, unsigned int* __restrict__ xbw,
        const void* __restrict__ raw, uint4* __restrict__ ep0w,
        uint4* __restrict__ cntw) {
    int is64 = detect64((const int*)raw);
    int i = blockIdx.x * 256 + threadIdx.x;
    if (i < (N_NODES * IN_DIM) / 8) {                       // 8 x-elems -> uint4
        const float4* xf = (const float4*)x;
        float4 a = xf[2 * i], b = xf[2 * i + 1];
        uint4 o;
        o.x = pack2bf(a.x, a.y);
        o.y = pack2bf(a.z, a.w);
        o.z = pack2bf(b.x, b.y);
        o.w = pack2bf(b.z, b.w);
        ((uint4*)xbw)[i] = o;
    }
    if (i < (N_NODES * CPAD) / 4)                           // 4 cnt words
        cntw[i] = make_uint4(0, 0, 0, 0);
    if (i < N_EDGES / 8) {                                  // 8 edges -> 2x uint4
        int e = i * 8;
        unsigned int o[8];
        if (is64) {
            const long long* r = (const long long*)raw;
#pragma unroll
            for (int k = 0; k < 8; k++) {
                unsigned int s = (unsigned int)(int)r[e + k] & 0xffffu;
                unsigned int d = (unsigned int)(int)r[N_EDGES + e + k] & 0xffffu;
                o[k] = s | (d << 16);
            }
        } else {
            const int* r = (const int*)raw;
#pragma unroll
            for (int k = 0; k < 8; k++) {
                unsigned int s = (unsigned int)r[e + k] & 0xffffu;
                unsigned int d = (unsigned int)r[N_EDGES + e + k] & 0xffffu;
                o[k] = s | (d << 16);
            }
        }
        ep0w[2 * i]     = make_uint4(o[0], o[1], o[2], o[3]);
        ep0w[2 * i + 1] = make_uint4(o[4], o[5], o[6], o[7]);
    }
}

// ---------------------------------------------------------------------------
// hist (VECTORIZED): 4 edges per thread via one uint4 load. XCD-partitioned
// (xcd = b%8 owns dst range -> atomics local to one XCD's L2); the atomic's
// return value IS the edge's within-node arrival rank.
__global__ __launch_bounds__(256) void hist_kernel(const uint4* __restrict__ ep0w,
                                                   int* __restrict__ cnt,
                                                   unsigned short* __restrict__ rank) {
    int xcd = blockIdx.x % N_XCD;
    int sl  = blockIdx.x / N_XCD;
    int lo  = xcd * NPX, hi = lo + NPX;
    int base = sl * SLICE;
#pragma unroll
    for (int j = 0; j < SLICE / 1024; j++) {
        int e = base + j * 1024 + threadIdx.x * 4;
        if (e < N_EDGES) {
            uint4 q = ep0w[e >> 2];
            int d0 = (int)(q.x >> 16), d1 = (int)(q.y >> 16);
            int d2 = (int)(q.z >> 16), d3 = (int)(q.w >> 16);
            if (d0 >= lo && d0 < hi)
                rank[e]     = (unsigned short)atomicAdd(&cnt[(size_t)d0 * CPAD], 1);
            if (d1 >= lo && d1 < hi)
                rank[e + 1] = (unsigned short)atomicAdd(&cnt[(size_t)d1 * CPAD], 1);
            if (d2 >= lo && d2 < hi)
                rank[e + 2] = (unsigned short)atomicAdd(&cnt[(size_t)d2 * CPAD], 1);
            if (d3 >= lo && d3 < hi)
                rank[e + 3] = (unsigned short)atomicAdd(&cnt[(size_t)d3 * CPAD], 1);
        }
    }
}

// ---------------------------------------------------------------------------
// scan1: block-local exclusive scan of cnt (padded) -> rowptr, bsum, dinv.
__global__ void scan1_kernel(const int* __restrict__ cnt, int* __restrict__ rowptr,
                             int* __restrict__ bsum, float* __restrict__ dinv) {
    __shared__ int s[SCAN_B];
    int t = threadIdx.x;
    int g = blockIdx.x * SCAN_B + t;
    int v = (g < N_NODES) ? cnt[(size_t)g * CPAD] : 0;
    if (g < N_NODES) dinv[g] = rsqrtf((float)(v + 1));   // +1 self loop
    s[t] = v;
    __syncthreads();
    for (int o = 1; o < SCAN_B; o <<= 1) {
        int add = (t >= o) ? s[t - o] : 0;
        __syncthreads();
        s[t] += add;
        __syncthreads();
    }
    if (g < N_NODES) rowptr[g] = s[t] - v;
    if (t == SCAN_B - 1) bsum[blockIdx.x] = s[t];
}

// scan23: each block redundantly scans the 196 bsums in LDS, applies offset.
__global__ void scan23_kernel(int* __restrict__ rowptr, const int* __restrict__ bsum) {
    __shared__ int s[256];
    int t = threadIdx.x;
    int v = (t < NB_SCAN) ? bsum[t] : 0;
    s[t] = v;
    __syncthreads();
    for (int o = 1; o < 256; o <<= 1) {
        int add = (t >= o) ? s[t - o] : 0;
        __syncthreads();
        s[t] += add;
        __syncthreads();
    }
    int excl = s[blockIdx.x] - bsum[blockIdx.x];
    int g = blockIdx.x * SCAN_B + t;
    if (g < N_NODES) rowptr[g] += excl;
    if (g == 0) rowptr[N_NODES] = N_EDGES;
}

// ---------------------------------------------------------------------------
// scatter (VECTORIZED): 4 edges per thread. Deterministic, no atomics:
// slot = rowptr[dst] + rank.
__global__ __launch_bounds__(256) void scatter_kernel(
        const uint4* __restrict__ ep0w, const unsigned short* __restrict__ rank,
        const int* __restrict__ rowptr, const float* __restrict__ dinv,
        int2* __restrict__ ep) {
    int base = blockIdx.x * SLICE;
#pragma unroll
    for (int j = 0; j < SLICE / 1024; j++) {
        int e = base + j * 1024 + threadIdx.x * 4;
        if (e < N_EDGES) {
            uint4 q = ep0w[e >> 2];
            uint2 rw = *(const uint2*)(rank + e);
            int s0 = (int)(q.x & 0xffffu), d0 = (int)(q.x >> 16);
            int s1 = (int)(q.y & 0xffffu), d1 = (int)(q.y >> 16);
            int s2 = (int)(q.z & 0xffffu), d2 = (int)(q.z >> 16);
            int s3 = (int)(q.w & 0xffffu), d3 = (int)(q.w >> 16);
            int r0 = (int)(rw.x & 0xffffu), r1 = (int)(rw.x >> 16);
            int r2 = (int)(rw.y & 0xffffu), r3 = (int)(rw.y >> 16);
            ep[rowptr[d0] + r0] = make_int2(s0, __float_as_int(dinv[s0]));
            ep[rowptr[d1] + r1] = make_int2(s1, __float_as_int(dinv[s1]));
            ep[rowptr[d2] + r2] = make_int2(s2, __float_as_int(dinv[s2]));
            ep[rowptr[d3] + r3] = make_int2(s3, __float_as_int(dinv[s3]));
        }
    }
}

// ---------------------------------------------------------------------------
// Dual-node 64-wide aggregation (unchanged from R9): two nodes' batch loops
// interleaved -> 8 gathers in flight. uint2 gathers: 16 lanes x 8B = 128B row.
__device__ __forceinline__ void agg_dual64(
        int e0A, int e1A, int2 prA, int e0B, int e1B, int2 prB,
        const int2* __restrict__ ep, const uint2* __restrict__ g2,
        int lane, int gsel, int c, float accA[4], float accB[4]) {
    int bA = e0A, bB = e0B;
    while (bA < e1A || bB < e1B) {
        int cA = e1A - bA; cA = cA < 0 ? 0 : (cA > 64 ? 64 : cA);
        int cB = e1B - bB; cB = cB < 0 ? 0 : (cB > 64 ? 64 : cB);
        int mj = cA > cB ? cA : cB;
        for (int j = 0; j < mj; j += 16) {
            uint2 fA[4], fB[4]; float wA[4], wB[4];
#pragma unroll
            for (int u = 0; u < 4; u++) {
                int idx = j + u * 4 + gsel;
                int clA = idx < cA ? idx : (cA > 0 ? cA - 1 : 0);
                int clB = idx < cB ? idx : (cB > 0 ? cB - 1 : 0);
                int sA  = __builtin_amdgcn_ds_bpermute(clA << 2, prA.x);
                int wwA = __builtin_amdgcn_ds_bpermute(clA << 2, prA.y);
                int sB  = __builtin_amdgcn_ds_bpermute(clB << 2, prB.x);
                int wwB = __builtin_amdgcn_ds_bpermute(clB << 2, prB.y);
                wA[u] = idx < cA ? __int_as_float(wwA) : 0.0f;
                wB[u] = idx < cB ? __int_as_float(wwB) : 0.0f;
                fA[u] = g2[(size_t)sA * 16 + c];
                fB[u] = g2[(size_t)sB * 16 + c];
            }
#pragma unroll
            for (int u = 0; u < 4; u++) {
                accA[0] = fmaf(wA[u], __uint_as_float(fA[u].x << 16),         accA[0]);
                accA[1] = fmaf(wA[u], __uint_as_float(fA[u].x & 0xffff0000u), accA[1]);
                accA[2] = fmaf(wA[u], __uint_as_float(fA[u].y << 16),         accA[2]);
                accA[3] = fmaf(wA[u], __uint_as_float(fA[u].y & 0xffff0000u), accA[3]);
                accB[0] = fmaf(wB[u], __uint_as_float(fB[u].x << 16),         accB[0]);
                accB[1] = fmaf(wB[u], __uint_as_float(fB[u].x & 0xffff0000u), accB[1]);
                accB[2] = fmaf(wB[u], __uint_as_float(fB[u].y << 16),         accB[2]);
                accB[3] = fmaf(wB[u], __uint_as_float(fB[u].y & 0xffff0000u), accB[3]);
            }
        }
        bA += 64; bB += 64;
        if (bA < e1A) { int i2 = bA + lane; prA = ep[i2 < e1A ? i2 : e1A - 1]; }
        if (bB < e1B) { int i2 = bB + lane; prB = ep[i2 < e1B ? i2 : e1B - 1]; }
    }
}

// Dual-node 32-wide aggregation: 8 lanes x 8B = 64B row, 8 edges/load.
__device__ __forceinline__ void agg_dual32(
        int e0A, int e1A, int2 prA, int e0B, int e1B, int2 prB,
        const int2* __restrict__ ep, const uint2* __restrict__ x2,
        int lane, int gsel, int c, float accA[4], float accB[4]) {
    int bA = e0A, bB = e0B;
    while (bA < e1A || bB < e1B) {
        int cA = e1A - bA; cA = cA < 0 ? 0 : (cA > 64 ? 64 : cA);
        int cB = e1B - bB; cB = cB < 0 ? 0 : (cB > 64 ? 64 : cB);
        int mj = cA > cB ? cA : cB;
        for (int j = 0; j < mj; j += 16) {
            uint2 fA[2], fB[2]; float wA[2], wB[2];
#pragma unroll
            for (int u = 0; u < 2; u++) {
                int idx = j + u * 8 + gsel;
                int clA = idx < cA ? idx : (cA > 0 ? cA - 1 : 0);
                int clB = idx < cB ? idx : (cB > 0 ? cB - 1 : 0);
                int sA  = __builtin_amdgcn_ds_bpermute(clA << 2, prA.x);
                int wwA = __builtin_amdgcn_ds_bpermute(clA << 2, prA.y);
                int sB  = __builtin_amdgcn_ds_bpermute(clB << 2, prB.x);
                int wwB = __builtin_amdgcn_ds_bpermute(clB << 2, prB.y);
                wA[u] = idx < cA ? __int_as_float(wwA) : 0.0f;
                wB[u] = idx < cB ? __int_as_float(wwB) : 0.0f;
                fA[u] = x2[(size_t)sA * 8 + c];
                fB[u] = x2[(size_t)sB * 8 + c];
            }
#pragma unroll
            for (int u = 0; u < 2; u++) {
                accA[0] = fmaf(wA[u], __uint_as_float(fA[u].x << 16),         accA[0]);
                accA[1] = fmaf(wA[u], __uint_as_float(fA[u].x & 0xffff0000u), accA[1]);
                accA[2] = fmaf(wA[u], __uint_as_float(fA[u].y << 16),         accA[2]);
                accA[3] = fmaf(wA[u], __uint_as_float(fA[u].y & 0xffff0000u), accA[3]);
                accB[0] = fmaf(wB[u], __uint_as_float(fB[u].x << 16),         accB[0]);
                accB[1] = fmaf(wB[u], __uint_as_float(fB[u].x & 0xffff0000u), accB[1]);
                accB[2] = fmaf(wB[u], __uint_as_float(fB[u].y << 16),         accB[2]);
                accB[3] = fmaf(wB[u], __uint_as_float(fB[u].y & 0xffff0000u), accB[3]);
            }
        }
        bA += 64; bB += 64;
        if (bA < e1A) { int i2 = bA + lane; prA = ep[i2 < e1A ? i2 : e1A - 1]; }
        if (bB < e1B) { int i2 = bB + lane; prB = ep[i2 < e1B ? i2 : e1B - 1]; }
    }
}

// Node-state loader (exec-masked first edge batch).
#define LOAD_STATE(v, e0, e1, dv, hv, pr, HLOAD)                            \
    {                                                                       \
        e0 = rowptr[v]; e1 = rowptr[v + 1];                                 \
        dv = dinv[v];                                                       \
        hv = HLOAD;                                                         \
        if (lane < e1 - e0) pr = ep[e0 + lane];                             \
    }

// ---------------------------------------------------------------------------
// Fused layer 1: q = normAgg(xb) [32-wide], out = relu(q @ W1 + b1).
__global__ __launch_bounds__(256) void fused_layer32_kernel(
        const int* __restrict__ rowptr, const int2* __restrict__ ep,
        const float* __restrict__ dinv, const unsigned short* __restrict__ xb,
        const float* __restrict__ W1, const float* __restrict__ b1,
        unsigned short* __restrict__ out) {
    __shared__ float sq[4][2][IN_DIM];
    int lane = threadIdx.x & 63;
    int wav  = threadIdx.x >> 6;
    int gsel = lane >> 3;                                    // 0..7
    int c    = lane & 7;                                     // 8 x uint2 = 64B row
    const uint2* x2 = (const uint2*)xb;
    float wcol[IN_DIM];
#pragma unroll
    for (int k = 0; k < IN_DIM; k++) wcol[k] = W1[k * 64 + lane];
    float bb = b1[lane];
    int wid = __builtin_amdgcn_readfirstlane((int)((blockIdx.x * blockDim.x + threadIdx.x) >> 6));
    int nw  = (gridDim.x * blockDim.x) >> 6;
    int vA = wid;
    if (vA >= N_NODES) return;
    int e0A = 0, e1A = 0, e0B = 0, e1B = 0;
    float dvA = 0.0f, dvB = 0.0f;
    uint2 hvA = make_uint2(0, 0), hvB = make_uint2(0, 0);
    int2 prA = make_int2(0, 0), prB = make_int2(0, 0);
    LOAD_STATE(vA, e0A, e1A, dvA, hvA, prA, x2[(size_t)vA * 8 + c])
    {
        int vB = vA + nw;
        if (vB < N_NODES)
            LOAD_STATE(vB, e0B, e1B, dvB, hvB, prB, x2[(size_t)vB * 8 + c])
    }
    while (vA < N_NODES) {
        int vB = vA + nw;
        int vA2 = vA + 2 * nw;
        int e0A2 = 0, e1A2 = 0, e0B2 = 0, e1B2 = 0;
        float dvA2 = 0.0f, dvB2 = 0.0f;
        uint2 hvA2 = make_uint2(0, 0), hvB2 = make_uint2(0, 0);
        int2 prA2 = make_int2(0, 0), prB2 = make_int2(0, 0);
        if (vA2 < N_NODES)
            LOAD_STATE(vA2, e0A2, e1A2, dvA2, hvA2, prA2, x2[(size_t)vA2 * 8 + c])
        if (vA2 + nw < N_NODES) {
            int vB2 = vA2 + nw;
            LOAD_STATE(vB2, e0B2, e1B2, dvB2, hvB2, prB2, x2[(size_t)vB2 * 8 + c])
        }
        float svA = (gsel == 0) ? dvA : 0.0f;
        float svB = (gsel == 0) ? dvB : 0.0f;
        float accA[4], accB[4];
        accA[0] = svA * __uint_as_float(hvA.x << 16);
        accA[1] = svA * __uint_as_float(hvA.x & 0xffff0000u);
        accA[2] = svA * __uint_as_float(hvA.y << 16);
        accA[3] = svA * __uint_as_float(hvA.y & 0xffff0000u);
        accB[0] = svB * __uint_as_float(hvB.x << 16);
        accB[1] = svB * __uint_as_float(hvB.x & 0xffff0000u);
        accB[2] = svB * __uint_as_float(hvB.y << 16);
        accB[3] = svB * __uint_as_float(hvB.y & 0xffff0000u);
        agg_dual32(e0A, e1A, prA, e0B, e1B, prB, ep, x2, lane, gsel, c, accA, accB);
#pragma unroll
        for (int i = 0; i < 4; i++) {
            accA[i] += __shfl_xor(accA[i], 8);
            accA[i] += __shfl_xor(accA[i], 16);
            accA[i] += __shfl_xor(accA[i], 32);
            accB[i] += __shfl_xor(accB[i], 8);
            accB[i] += __shfl_xor(accB[i], 16);
            accB[i] += __shfl_xor(accB[i], 32);
        }
        if (lane < 8) {
            ((float4*)(&sq[wav][0][0]))[c] =
                make_float4(dvA * accA[0], dvA * accA[1], dvA * accA[2], dvA * accA[3]);
            ((float4*)(&sq[wav][1][0]))[c] =
                make_float4(dvB * accB[0], dvB * accB[1], dvB * accB[2], dvB * accB[3]);
        }
        float oA = bb, oB = bb;
        const float4* qA = (const float4*)(&sq[wav][0][0]);
        const float4* qB = (const float4*)(&sq[wav][1][0]);
#pragma unroll
        for (int k = 0; k < IN_DIM / 4; k++) {
            float4 ta = qA[k], tb = qB[k];
            oA = fmaf(ta.x, wcol[4 * k + 0], oA);
            oA = fmaf(ta.y, wcol[4 * k + 1], oA);
            oA = fmaf(ta.z, wcol[4 * k + 2], oA);
            oA = fmaf(ta.w, wcol[4 * k + 3], oA);
            oB = fmaf(tb.x, wcol[4 * k + 0], oB);
            oB = fmaf(tb.y, wcol[4 * k + 1], oB);
            oB = fmaf(tb.z, wcol[4 * k + 2], oB);
            oB = fmaf(tb.w, wcol[4 * k + 3], oB);
        }
        out[(size_t)vA * 64 + lane] = f2bf(fmaxf(oA, 0.0f));
        if (vB < N_NODES) out[(size_t)vB * 64 + lane] = f2bf(fmaxf(oB, 0.0f));
        vA = vA2;
        e0A = e0A2; e1A = e1A2; dvA = dvA2; hvA = hvA2; prA = prA2;
        e0B = e0B2; e1B = e1B2; dvB = dvB2; hvB = hvB2; prB = prB2;
    }
}

// Fused layer 2: q = normAgg(g) [64-wide], out = relu(q @ W + b). Dual-node.
__global__ __launch_bounds__(256) void fused_layer64_kernel(
        const int* __restrict__ rowptr, const int2* __restrict__ ep,
        const float* __restrict__ dinv, const unsigned short* __restrict__ g,
        const float* __restrict__ W, const float* __restrict__ bias,
        unsigned short* __restrict__ out) {
    __shared__ float sq[4][2][HIDDEN];
    int lane = threadIdx.x & 63;
    int wav  = threadIdx.x >> 6;
    int gsel = lane >> 4;                                    // 0..3
    int c    = lane & 15;                                    // 16 x uint2 = 128B row
    const uint2* g2 = (const uint2*)g;
    float wcol[HIDDEN];
#pragma unroll
    for (int k = 0; k < HIDDEN; k++) wcol[k] = W[k * 64 + lane];
    float bb = bias[lane];
    int wid = __builtin_amdgcn_readfirstlane((int)((blockIdx.x * blockDim.x + threadIdx.x) >> 6));
    int nw  = (gridDim.x * blockDim.x) >> 6;
    int vA = wid;
    if (vA >= N_NODES) return;
    int e0A = 0, e1A = 0, e0B = 0, e1B = 0;
    float dvA = 0.0f, dvB = 0.0f;
    uint2 hvA = make_uint2(0, 0), hvB = make_uint2(0, 0);
    int2 prA = make_int2(0, 0), prB = make_int2(0, 0);
    LOAD_STATE(vA, e0A, e1A, dvA, hvA, prA, g2[(size_t)vA * 16 + c])
    {
        int vB = vA + nw;
        if (vB < N_NODES)
            LOAD_STATE(vB, e0B, e1B, dvB, hvB, prB, g2[(size_t)vB * 16 + c])
    }
    while (vA < N_NODES) {
        int vB = vA + nw;
        int vA2 = vA + 2 * nw;
        int e0A2 = 0, e1A2 = 0, e0B2 = 0, e1B2 = 0;
        float dvA2 = 0.0f, dvB2 = 0.0f;
        uint2 hvA2 = make_uint2(0, 0), hvB2 = make_uint2(0, 0);
        int2 prA2 = make_int2(0, 0), prB2 = make_int2(0, 0);
        if (vA2 < N_NODES)
            LOAD_STATE(vA2, e0A2, e1A2, dvA2, hvA2, prA2, g2[(size_t)vA2 * 16 + c])
        if (vA2 + nw < N_NODES) {
            int vB2 = vA2 + nw;
            LOAD_STATE(vB2, e0B2, e1B2, dvB2, hvB2, prB2, g2[(size_t)vB2 * 16 + c])
        }
        float svA = (gsel == 0) ? dvA : 0.0f;
        float svB = (gsel == 0) ? dvB : 0.0f;
        float accA[4], accB[4];
        accA[0] = svA * __uint_as_float(hvA.x << 16);
        accA[1] = svA * __uint_as_float(hvA.x & 0xffff0000u);
        accA[2] = svA * __uint_as_float(hvA.y << 16);
        accA[3] = svA * __uint_as_float(hvA.y & 0xffff0000u);
        accB[0] = svB * __uint_as_float(hvB.x << 16);
        accB[1] = svB * __uint_as_float(hvB.x & 0xffff0000u);
        accB[2] = svB * __uint_as_float(hvB.y << 16);
        accB[3] = svB * __uint_as_float(hvB.y & 0xffff0000u);
        agg_dual64(e0A, e1A, prA, e0B, e1B, prB, ep, g2, lane, gsel, c, accA, accB);
#pragma unroll
        for (int i = 0; i < 4; i++) {
            accA[i] += __shfl_xor(accA[i], 16);
            accA[i] += __shfl_xor(accA[i], 32);
            accB[i] += __shfl_xor(accB[i], 16);
            accB[i] += __shfl_xor(accB[i], 32);
        }
        if (lane < 16) {
            ((float4*)(&sq[wav][0][0]))[c] =
                make_float4(dvA * accA[0], dvA * accA[1], dvA * accA[2], dvA * accA[3]);
            ((float4*)(&sq[wav][1][0]))[c] =
                make_float4(dvB * accB[0], dvB * accB[1], dvB * accB[2], dvB * accB[3]);
        }
        float oA = bb, oB = bb;
        const float4* qA = (const float4*)(&sq[wav][0][0]);
        const float4* qB = (const float4*)(&sq[wav][1][0]);
#pragma unroll
        for (int k = 0; k < HIDDEN / 4; k++) {
            float4 ta = qA[k], tb = qB[k];
            oA = fmaf(ta.x, wcol[4 * k + 0], oA);
            oA = fmaf(ta.y, wcol[4 * k + 1], oA);
            oA = fmaf(ta.z, wcol[4 * k + 2], oA);
            oA = fmaf(ta.w, wcol[4 * k + 3], oA);
            oB = fmaf(tb.x, wcol[4 * k + 0], oB);
            oB = fmaf(tb.y, wcol[4 * k + 1], oB);
            oB = fmaf(tb.z, wcol[4 * k + 2], oB);
            oB = fmaf(tb.w, wcol[4 * k + 3], oB);
        }
        out[(size_t)vA * 64 + lane] = f2bf(fmaxf(oA, 0.0f));
        if (vB < N_NODES) out[(size_t)vB * 64 + lane] = f2bf(fmaxf(oB, 0.0f));
        vA = vA2;
        e0A = e0A2; e1A = e1A2; dvA = dvA2; hvA = hvA2; prA = prA2;
        e0B = e0B2; e1B = e1B2; dvB = dvB2; hvB = hvB2; prB = prB2;
    }
}

// Fused heads: q = normAgg(h2); mu (lanes<32) / lv (lanes>=32); z = mu+exp(.5lv)eps.
__global__ __launch_bounds__(256) void fused_head_kernel(
        const int* __restrict__ rowptr, const int2* __restrict__ ep,
        const float* __restrict__ dinv, const unsigned short* __restrict__ g,
        const float* __restrict__ Wmu, const float* __restrict__ Wlv,
        const float* __restrict__ bmu, const float* __restrict__ blv,
        const float* __restrict__ eps, float* __restrict__ outz) {
    __shared__ float sq[4][2][HIDDEN];
    int lane = threadIdx.x & 63;
    int wav  = threadIdx.x >> 6;
    int gsel = lane >> 4;
    int c    = lane & 15;
    int f = lane & 31;
    bool hi = lane >= 32;
    const uint2* g2 = (const uint2*)g;
    float wcol[HIDDEN];
#pragma unroll
    for (int k = 0; k < HIDDEN; k++)
        wcol[k] = hi ? Wlv[k * 32 + f] : Wmu[k * 32 + f];
    float bb = hi ? blv[f] : bmu[f];
    float* z  = outz;
    float* mu = outz + (size_t)N_NODES * Z_DIM;
    float* lv = outz + 2 * (size_t)N_NODES * Z_DIM;
    int wid = __builtin_amdgcn_readfirstlane((int)((blockIdx.x * blockDim.x + threadIdx.x) >> 6));
    int nw  = (gridDim.x * blockDim.x) >> 6;
    int vA = wid;
    if (vA >= N_NODES) return;
    int e0A = 0, e1A = 0, e0B = 0, e1B = 0;
    float dvA = 0.0f, dvB = 0.0f;
    uint2 hvA = make_uint2(0, 0), hvB = make_uint2(0, 0);
    int2 prA = make_int2(0, 0), prB = make_int2(0, 0);
    LOAD_STATE(vA, e0A, e1A, dvA, hvA, prA, g2[(size_t)vA * 16 + c])
    {
        int vB = vA + nw;
        if (vB < N_NODES)
            LOAD_STATE(vB, e0B, e1B, dvB, hvB, prB, g2[(size_t)vB * 16 + c])
    }
    while (vA < N_NODES) {
        int vB = vA + nw;
        int vA2 = vA + 2 * nw;
        int e0A2 = 0, e1A2 = 0, e0B2 = 0, e1B2 = 0;
        float dvA2 = 0.0f, dvB2 = 0.0f;
        uint2 hvA2 = make_uint2(0, 0), hvB2 = make_uint2(0, 0);
        int2 prA2 = make_int2(0, 0), prB2 = make_int2(0, 0);
        if (vA2 < N_NODES)
            LOAD_STATE(vA2, e0A2, e1A2, dvA2, hvA2, prA2, g2[(size_t)vA2 * 16 + c])
        if (vA2 + nw < N_NODES) {
            int vB2 = vA2 + nw;
            LOAD_STATE(vB2, e0B2, e1B2, dvB2, hvB2, prB2, g2[(size_t)vB2 * 16 + c])
        }
        float svA = (gsel == 0) ? dvA : 0.0f;
        float svB = (gsel == 0) ? dvB : 0.0f;
        float accA[4], accB[4];
        accA[0] = svA * __uint_as_float(hvA.x << 16);
        accA[1] = svA * __uint_as_float(hvA.x & 0xffff0000u);
        accA[2] = svA * __uint_as_float(hvA.y << 16);
        accA[3] = svA * __uint_as_float(hvA.y & 0xffff0000u);
        accB[0] = svB * __uint_as_float(hvB.x << 16);
        accB[1] = svB * __uint_as_float(hvB.x & 0xffff0000u);
        accB[2] = svB * __uint_as_float(hvB.y << 16);
        accB[3] = svB * __uint_as_float(hvB.y & 0xffff0000u);
        agg_dual64(e0A, e1A, prA, e0B, e1B, prB, ep, g2, lane, gsel, c, accA, accB);
#pragma unroll
        for (int i = 0; i < 4; i++) {
            accA[i] += __shfl_xor(accA[i], 16);
            accA[i] += __shfl_xor(accA[i], 32);
            accB[i] += __shfl_xor(accB[i], 16);
            accB[i] += __shfl_xor(accB[i], 32);
        }
        if (lane < 16) {
            ((float4*)(&sq[wav][0][0]))[c] =
                make_float4(dvA * accA[0], dvA * accA[1], dvA * accA[2], dvA * accA[3]);
            ((float4*)(&sq[wav][1][0]))[c] =
                make_float4(dvB * accB[0], dvB * accB[1], dvB * accB[2], dvB * accB[3]);
        }
        float mA = bb, mB = bb;
        const float4* qA = (const float4*)(&sq[wav][0][0]);
        const float4* qB = (const float4*)(&sq[wav][1][0]);
#pragma unroll
        for (int k = 0; k < HIDDEN / 4; k++) {
            float4 ta = qA[k], tb = qB[k];
            mA = fmaf(ta.x, wcol[4 * k + 0], mA);
            mA = fmaf(ta.y, wcol[4 * k + 1], mA);
            mA = fmaf(ta.z, wcol[4 * k + 2], mA);
            mA = fmaf(ta.w, wcol[4 * k + 3], mA);
            mB = fmaf(tb.x, wcol[4 * k + 0], mB);
            mB = fmaf(tb.y, wcol[4 * k + 1], mB);
            mB = fmaf(tb.z, wcol[4 * k + 2], mB);
            mB = fmaf(tb.w, wcol[4 * k + 3], mB);
        }
        {
            float ev = eps[(size_t)vA * Z_DIM + f];
            float t  = expf(0.5f * mA) * ev;
            float tlo = __shfl(t, lane | 32);
            size_t o = (size_t)vA * Z_DIM + f;
            if (!hi) { mu[o] = mA; z[o] = mA + tlo; }
            else     { lv[o] = mA; }
        }
        if (vB < N_NODES) {
            float ev = eps[(size_t)vB * Z_DIM + f];
            float t  = expf(0.5f * mB) * ev;
            float tlo = __shfl(t, lane | 32);
            size_t o = (size_t)vB * Z_DIM + f;
            if (!hi) { mu[o] = mB; z[o] = mB + tlo; }
            else     { lv[o] = mB; }
        }
        vA = vA2;
        e0A = e0A2; e1A = e1A2; dvA = dvA2; hvA = hvA2; prA = prA2;
        e0B = e0B2; e1B = e1B2; dvB = dvB2; hvB = hvB2; prB = prB2;
    }
}

// ---------------------------------------------------------------------------
extern "C" void kernel_launch(void* const* d_in, const int* in_sizes, int n_in,
                              void* d_out, int out_size, void* d_ws, size_t ws_size,
                              hipStream_t stream) {
    const float* x   = (const float*)d_in[0];
    const void*  ei  = d_in[1];
    const float* W1  = (const float*)d_in[2];
    const float* b1  = (const float*)d_in[3];
    const float* W2  = (const float*)d_in[4];
    const float* b2  = (const float*)d_in[5];
    const float* Wmu = (const float*)d_in[6];
    const float* bmu = (const float*)d_in[7];
    const float* Wlv = (const float*)d_in[8];
    const float* blv = (const float*)d_in[9];
    const float* eps = (const float*)d_in[10];
    float* out = (float*)d_out;
    (void)in_sizes; (void)n_in; (void)out_size; (void)ws_size;

    char* ws = (char*)d_ws;
    size_t off = 0;
    auto alloc = [&](size_t bytes) -> void* {
        void* p = ws + off;
        off += (bytes + 255) & ~(size_t)255;
        return p;
    };
    int2*           ep     = (int2*)alloc(sizeof(int2) * N_EDGES);       // 6.4 MB
    ushort2*        ep0    = (ushort2*)alloc(sizeof(ushort2) * N_EDGES); // 3.2 MB
    unsigned short* rank   = (unsigned short*)alloc(sizeof(short) * N_EDGES);  // 1.6 MB
    int*            rowptr = (int*)alloc(sizeof(int) * (N_NODES + 1));
    int*            cnt    = (int*)alloc(sizeof(int) * (size_t)N_NODES * CPAD); // 3.2 MB
    float*          dinv   = (float*)alloc(sizeof(float) * N_NODES);
    int*            bsum   = (int*)alloc(sizeof(int) * 256);
    unsigned short* xb     = (unsigned short*)alloc(sizeof(short) * (size_t)N_NODES * IN_DIM);  // 3.2 MB
    unsigned short* G      = (unsigned short*)alloc(sizeof(short) * (size_t)N_NODES * HIDDEN);  // 6.4 MB
    unsigned short* H      = (unsigned short*)alloc(sizeof(short) * (size_t)N_NODES * HIDDEN);  // 6.4 MB

    prep_a_kernel<<<PREP_B, 256, 0, stream>>>(x, (unsigned int*)xb, ei,
                                              (uint4*)ep0, (uint4*)cnt);
    hist_kernel<<<SCAT_B, 256, 0, stream>>>((const uint4*)ep0, cnt, rank);
    scan1_kernel<<<NB_SCAN, SCAN_B, 0, stream>>>(cnt, rowptr, bsum, dinv);
    scan23_kernel<<<NB_SCAN, SCAN_B, 0, stream>>>(rowptr, bsum);
    scatter_kernel<<<N_SLICE, 256, 0, stream>>>((const uint4*)ep0, rank, rowptr, dinv, ep);
    // Layer 1: h1 = relu((A_norm x) W1 + b1)
    fused_layer32_kernel<<<FB, 256, 0, stream>>>(rowptr, ep, dinv, xb, W1, b1, H);
    // Layer 2: h2 = relu((A_norm h1) W2 + b2)
    fused_layer64_kernel<<<FB, 256, 0, stream>>>(rowptr, ep, dinv, H, W2, b2, G);
    // Heads: q = A_norm h2 ; mu|lv = q@[Wmu|Wlv]+b ; z = mu + exp(.5 lv) eps
    fused_head_kernel<<<FB, 256, 0, stream>>>(rowptr, ep, dinv, G, Wmu, Wlv, bmu, blv, eps, out);
}